// Round 9
// baseline (7818.343 us; speedup 1.0000x reference)
//
#include <hip/hip_runtime.h>
#include <hip/hip_bf16.h>
#include <math.h>

// Problem constants
#define NB 8
#define NIN 256
#define NHID 256
#define NMEM 64
#define NSEQ 2048
#define NFEAT 64
#define NOUTCH 320        // NFEAT + NHID
#define NFFT 4096
#define KBINS 2049        // NSEQ + 1
#define OCH 32            // o-chunk size
#define NOCH 8            // 256 / 32

// ws layout (float offsets) — TOTAL 14.18 MB (within round-7 proven budget)
#define FFTU_OFF 0
#define FFTU_SZ (NB * NFEAT * KBINS * 2)               // 2,098,176 (8.4 MB)
#define UZ_OFF (FFTU_OFF + FFTU_SZ)                    // overlay: f64 W/Mk -> ubuf -> Z o-chunks
#define UZ_SZ (NB * OCH * KBINS * 2)                   // 1,049,088 (4.2 MB)
#define FHD_OFF (UZ_OFF + UZ_SZ)
#define FHD_SZ (NMEM * KBINS * 2)                      // 262,272 (1.05 MB)
#define TW_OFF (FHD_OFF + FHD_SZ)
#define TW_SZ (2048 * 2)                               // 16 KB
#define HBUF_OFF (TW_OFF + TW_SZ)
#define HBUF_SZ (NMEM * NSEQ)                          // 131,072 (0.52 MB)

// f64 outputs of kA (doubles, based at UZ_OFF; dead before ubuf is written)
#define DW_OFF   0        // [64 r][64 j] = Ad^r Bd
#define DMK_OFF  4096     // [32 k][64][64] = (Ad^64)^k

// padded LDS index for FFT arrays (breaks power-of-2 stride bank conflicts)
#define FIDX(i) ((i) + ((i) >> 5) + ((i) >> 10))
#define FFT_LDS 4240

// ---------------------------------------------------------------------------
// shared 4096-pt radix-2 DIT core (data already bit-reversed into XR/XI)
// ---------------------------------------------------------------------------
__device__ __forceinline__ void fft4096_core(float* XR, float* XI,
                                             const float2* TWS, bool inverse) {
#pragma unroll 1
  for (int s = 1; s <= 12; ++s) {
    int half = 1 << (s - 1);
    int shift = 12 - s;
#pragma unroll
    for (int q = 0; q < 8; ++q) {
      int bf = threadIdx.x + q * 256;
      int j = bf & (half - 1);
      int base = ((bf >> (s - 1)) << s) + j;
      float2 w = TWS[j << shift];
      float wr = w.x, wi = inverse ? -w.y : w.y;
      int i0 = FIDX(base), i1 = FIDX(base + half);
      float ar = XR[i0], ai = XI[i0];
      float br = XR[i1], bi = XI[i1];
      float tr = wr * br - wi * bi, ti = wr * bi + wi * br;
      XR[i0] = ar + tr; XI[i0] = ai + ti;
      XR[i1] = ar - tr; XI[i1] = ai - ti;
    }
    __syncthreads();
  }
}

// ---------------------------------------------------------------------------
// k0: tw[m] = exp(-2*pi*i*m/4096), m in [0,2048), double precision.
// ---------------------------------------------------------------------------
__global__ void k0_tw(float2* __restrict__ tw) {
  int m = blockIdx.x * 256 + threadIdx.x;
  if (m < 2048) {
    double ang = -2.0 * 3.14159265358979323846 * (double)m / 4096.0;
    tw[m] = make_float2((float)cos(ang), (float)sin(ang));
  }
}

// ---------------------------------------------------------------------------
// kA2: LDS-resident fp64 discretization (was 4ms: 235 global round-trips on
// 256 threads; now 1024 threads, 3x4225-double LDS buffers = 101.4 KB).
//  1) blk=[[A,B],[0,0]] (65x65); Taylor expm (29 terms, s squarings);
//     Ad,Bd rounded through f32 (as reference).
//  2) W[r]=Ad^r Bd (r<64); Ad64=Ad^64 (6 squarings); Mk[k]=(Ad64)^k (k<32).
// Outputs only W, Mk to global (for kB).
// ---------------------------------------------------------------------------
#define KA_NT 1024
__global__ __launch_bounds__(KA_NT) void kA2_expm(double* __restrict__ D) {
  extern __shared__ double lds[];
  double* Msh = lds;           // 4225
  double* Tsh = lds + 4225;    // 4225
  double* Esh = lds + 8450;    // 4225
  __shared__ double sh_scale;
  __shared__ int sh_s;
  const int tid = threadIdx.x;

  // 1) build blk matrix
  for (int e = tid; e < 4225; e += KA_NT) {
    int i = e / 65, j = e % 65;
    double val = 0.0;
    if (i < 64) {
      double R = (2.0 * i + 1.0) / 2048.0;
      if (j < 64) val = R * ((i < j) ? -1.0 : (((i - j) & 1) ? 1.0 : -1.0));
      else        val = R * ((i & 1) ? -1.0 : 1.0);   // Bc = R*(-1)^i
    }
    Msh[e] = val;
  }
  __syncthreads();
  // norm-1 (max column abs-sum)
  if (tid < 65) {
    double cs = 0.0;
    for (int i = 0; i < 65; ++i) cs += fabs(Msh[i * 65 + tid]);
    Tsh[tid] = cs;
  }
  __syncthreads();
  if (tid == 0) {
    double norm = 0.0;
    for (int j = 0; j < 65; ++j) if (Tsh[j] > norm) norm = Tsh[j];
    if (norm < 1e-16) norm = 1e-16;
    int s = (int)ceil(log2(norm)) + 1;
    if (s < 0) s = 0;
    sh_s = s;
    double sc = 1.0;
    for (int q = 0; q < s; ++q) sc *= 0.5;
    sh_scale = sc;
  }
  __syncthreads();
  const double scale = sh_scale;
  const int s = sh_s;
  for (int e = tid; e < 4225; e += KA_NT) {
    int i = e / 65, j = e % 65;
    Msh[e] *= scale;
    double id = (i == j) ? 1.0 : 0.0;
    Tsh[e] = id; Esh[e] = id;
  }
  __syncthreads();

  // 2) Taylor: T = T@M/k; E += T   (29 terms)
  for (int k = 1; k <= 29; ++k) {
    double tn[5];
#pragma unroll
    for (int r = 0; r < 5; ++r) {
      int e = tid + r * KA_NT;
      double dot = 0.0;
      if (e < 4225) {
        int i = e / 65, j = e % 65;
        for (int l = 0; l < 65; ++l) dot += Tsh[i * 65 + l] * Msh[l * 65 + j];
        dot /= (double)k;
      }
      tn[r] = dot;
    }
    __syncthreads();
#pragma unroll
    for (int r = 0; r < 5; ++r) {
      int e = tid + r * KA_NT;
      if (e < 4225) { Tsh[e] = tn[r]; Esh[e] += tn[r]; }
    }
    __syncthreads();
  }
  // 3) s squarings: E = E@E
  for (int q = 0; q < s; ++q) {
    double tn[5];
#pragma unroll
    for (int r = 0; r < 5; ++r) {
      int e = tid + r * KA_NT;
      double dot = 0.0;
      if (e < 4225) {
        int i = e / 65, j = e % 65;
        for (int l = 0; l < 65; ++l) dot += Esh[i * 65 + l] * Esh[l * 65 + j];
      }
      tn[r] = dot;
    }
    __syncthreads();
#pragma unroll
    for (int r = 0; r < 5; ++r) {
      int e = tid + r * KA_NT;
      if (e < 4225) Esh[e] = tn[r];
    }
    __syncthreads();
  }
  // 4) extract Ad (f32-rounded) into Msh, Bd into Tsh[0..63]
  {
    double ad[4];
#pragma unroll
    for (int r = 0; r < 4; ++r) {
      int e = tid + r * KA_NT;           // e < 4096 always
      ad[r] = (double)(float)Esh[(e >> 6) * 65 + (e & 63)];
    }
    double bd = (tid < 64) ? (double)(float)Esh[tid * 65 + 64] : 0.0;
    __syncthreads();
#pragma unroll
    for (int r = 0; r < 4; ++r) { int e = tid + r * KA_NT; Msh[e] = ad[r]; }
    if (tid < 64) Tsh[tid] = bd;
    __syncthreads();
  }
  // 5) W chain in Esh: W[r] = Ad^r Bd
  if (tid < 64) Esh[tid] = Tsh[tid];
  __syncthreads();
  for (int r = 1; r < 64; ++r) {
    double dot = 0.0;
    if (tid < 64) {
      for (int j = 0; j < 64; ++j)
        dot += Msh[tid * 64 + j] * Esh[(r - 1) * 64 + j];
    }
    __syncthreads();
    if (tid < 64) Esh[r * 64 + tid] = dot;
    __syncthreads();
  }
  for (int e = tid; e < 4096; e += KA_NT) D[DW_OFF + e] = Esh[e];
  // 6) Ad64 = Ad^64: Tsh <- Ad, 6 squarings
  for (int e = tid; e < 4096; e += KA_NT) Tsh[e] = Msh[e];
  __syncthreads();
  for (int q = 0; q < 6; ++q) {
    double tn[4];
#pragma unroll
    for (int r = 0; r < 4; ++r) {
      int e = tid + r * KA_NT;
      int i = e >> 6, j = e & 63;
      double dot = 0.0;
      for (int l = 0; l < 64; ++l) dot += Tsh[i * 64 + l] * Tsh[l * 64 + j];
      tn[r] = dot;
    }
    __syncthreads();
#pragma unroll
    for (int r = 0; r < 4; ++r) { int e = tid + r * KA_NT; Tsh[e] = tn[r]; }
    __syncthreads();
  }
  // 7) Mk chain in Esh (W already flushed): Mk[0]=I; Mk[k]=Mk[k-1]@Ad64
  for (int e = tid; e < 4096; e += KA_NT) {
    double id = ((e >> 6) == (e & 63)) ? 1.0 : 0.0;
    Esh[e] = id;
    D[DMK_OFF + e] = id;
  }
  __syncthreads();
  for (int k = 1; k < 32; ++k) {
    double tn[4];
#pragma unroll
    for (int r = 0; r < 4; ++r) {
      int e = tid + r * KA_NT;
      int i = e >> 6, j = e & 63;
      double dot = 0.0;
      for (int l = 0; l < 64; ++l) dot += Esh[i * 64 + l] * Tsh[l * 64 + j];
      tn[r] = dot;
    }
    __syncthreads();
#pragma unroll
    for (int r = 0; r < 4; ++r) {
      int e = tid + r * KA_NT;
      Esh[e] = tn[r];
      D[DMK_OFF + (size_t)k * 4096 + e] = tn[r];
    }
    __syncthreads();
  }
}

// ---------------------------------------------------------------------------
// kB: parallel impulse response. Block k (of 32): H[i, 64k+r] = Mk[k] @ W[r].
// ---------------------------------------------------------------------------
__global__ __launch_bounds__(256) void kB_cols(const double* __restrict__ D,
                                               float* __restrict__ H) {
  const double* W = D + DW_OFF;
  const double* Mrow = D + DMK_OFF + (size_t)blockIdx.x * 4096;
  __shared__ double Ms[4096];
  const int tid = threadIdx.x;
  for (int e = tid; e < 4096; e += 256) Ms[e] = Mrow[e];
  __syncthreads();
  const int c0 = blockIdx.x * 64;
  for (int e = tid; e < 4096; e += 256) {
    int i = e >> 6, r = e & 63;
    double dot = 0.0;
#pragma unroll 16
    for (int j = 0; j < 64; ++j) dot += Ms[i * 64 + j] * W[r * 64 + j];
    H[(size_t)i * NSEQ + c0 + r] = (float)dot;
  }
}

// ---------------------------------------------------------------------------
// kC: fHd[mi,k] = rfft(H[mi,:], n=4096)[k] via LDS FFT. 1 block/row.
// ---------------------------------------------------------------------------
__global__ __launch_bounds__(256) void kC_fft(const float* __restrict__ H,
                                              const float2* __restrict__ tw,
                                              float* __restrict__ fHd) {
  __shared__ float XR[FFT_LDS], XI[FFT_LDS];
  __shared__ float2 TWS[2048];
  const int tid = threadIdx.x;
  const int mi = blockIdx.x;
  const float* src = H + (size_t)mi * NSEQ;
  for (int i = tid; i < NFFT; i += 256) { XR[FIDX(i)] = 0.f; XI[FIDX(i)] = 0.f; }
  for (int i = tid; i < 2048; i += 256) TWS[i] = tw[i];
  __syncthreads();
  for (int i = tid; i < NSEQ; i += 256) {
    int r = __brev((unsigned)i) >> 20;
    XR[FIDX(r)] = src[i];
  }
  __syncthreads();
  fft4096_core(XR, XI, TWS, false);
  float2* dst = (float2*)fHd + (size_t)mi * KBINS;
  for (int k = tid; k < KBINS; k += 256)
    dst[k] = make_float2(XR[FIDX(k)], XI[FIDX(k)]);
}

// ---------------------------------------------------------------------------
// k1t: tiled GEMM out[b,o,s] = bias + sum_i Wu_w[o,i]*x[b,i,s]
//   o<256 -> dout = acc + Wu_b + Wh_b ; o>=256 -> ubuf = relu(acc + Wu_b)
// ---------------------------------------------------------------------------
__global__ __launch_bounds__(256) void k1t(
    const float* __restrict__ x, const float* __restrict__ Wuw,
    const float* __restrict__ Wub, const float* __restrict__ Whb,
    float* __restrict__ dout, float* __restrict__ ubuf) {
  __shared__ float xs[32][128];
  __shared__ float wsh[32][68];
  const int tid = threadIdx.x;
  const int b = blockIdx.z;
  const int o0 = blockIdx.y * 64;
  const int s0 = blockIdx.x * 128;
  const int sx = tid & 15, oy = tid >> 4;
  float acc[4][8];
#pragma unroll
  for (int j = 0; j < 4; ++j)
#pragma unroll
    for (int l = 0; l < 8; ++l) acc[j][l] = 0.f;

  for (int i0 = 0; i0 < 256; i0 += 32) {
#pragma unroll
    for (int e4 = tid; e4 < 1024; e4 += 256) {
      int ii = e4 >> 5, ss4 = (e4 & 31) << 2;
      float4 v = *(const float4*)&x[(size_t)(b * NIN + i0 + ii) * NSEQ + s0 + ss4];
      *(float4*)&xs[ii][ss4] = v;
    }
#pragma unroll
    for (int e4 = tid; e4 < 512; e4 += 256) {
      int oj = e4 >> 3, ii4 = (e4 & 7) << 2;
      float4 v = *(const float4*)&Wuw[(o0 + oj) * NIN + i0 + ii4];
      wsh[ii4][oj] = v.x; wsh[ii4 + 1][oj] = v.y;
      wsh[ii4 + 2][oj] = v.z; wsh[ii4 + 3][oj] = v.w;
    }
    __syncthreads();
#pragma unroll 8
    for (int kk = 0; kk < 32; ++kk) {
      float4 a = *(const float4*)&wsh[kk][oy * 4];
      float4 b0 = *(const float4*)&xs[kk][sx * 4];
      float4 b1 = *(const float4*)&xs[kk][64 + sx * 4];
      float av[4] = {a.x, a.y, a.z, a.w};
      float bv[8] = {b0.x, b0.y, b0.z, b0.w, b1.x, b1.y, b1.z, b1.w};
#pragma unroll
      for (int j = 0; j < 4; ++j)
#pragma unroll
        for (int l = 0; l < 8; ++l) acc[j][l] = fmaf(av[j], bv[l], acc[j][l]);
    }
    __syncthreads();
  }
#pragma unroll
  for (int j = 0; j < 4; ++j) {
    int o = o0 + oy * 4 + j;
    if (o < NHID) {
      float bias = Wub[o] + Whb[o];
      size_t base = ((size_t)b * NHID + o) * NSEQ + s0;
      float4 v0 = make_float4(acc[j][0] + bias, acc[j][1] + bias,
                              acc[j][2] + bias, acc[j][3] + bias);
      float4 v1 = make_float4(acc[j][4] + bias, acc[j][5] + bias,
                              acc[j][6] + bias, acc[j][7] + bias);
      *(float4*)&dout[base + sx * 4] = v0;
      *(float4*)&dout[base + 64 + sx * 4] = v1;
    } else {
      float bias = Wub[o];
      size_t base = ((size_t)b * NFEAT + (o - NHID)) * NSEQ + s0;
      float4 v0 = make_float4(fmaxf(acc[j][0] + bias, 0.f), fmaxf(acc[j][1] + bias, 0.f),
                              fmaxf(acc[j][2] + bias, 0.f), fmaxf(acc[j][3] + bias, 0.f));
      float4 v1 = make_float4(fmaxf(acc[j][4] + bias, 0.f), fmaxf(acc[j][5] + bias, 0.f),
                              fmaxf(acc[j][6] + bias, 0.f), fmaxf(acc[j][7] + bias, 0.f));
      *(float4*)&ubuf[base + sx * 4] = v0;
      *(float4*)&ubuf[base + 64 + sx * 4] = v1;
    }
  }
}

// ---------------------------------------------------------------------------
// k2f: fft_u[b,f,k] = rfft(ubuf[b,f,:], n=4096)[k] via LDS FFT. 1 block/row.
// ---------------------------------------------------------------------------
__global__ __launch_bounds__(256) void k2f(
    const float* __restrict__ ubuf, const float2* __restrict__ tw,
    float* __restrict__ fftu) {
  __shared__ float XR[FFT_LDS], XI[FFT_LDS];
  __shared__ float2 TWS[2048];
  const int tid = threadIdx.x;
  const int b = blockIdx.x >> 6, f = blockIdx.x & 63;
  const float* src = ubuf + ((size_t)b * NFEAT + f) * NSEQ;
  for (int i = tid; i < NFFT; i += 256) { XR[FIDX(i)] = 0.f; XI[FIDX(i)] = 0.f; }
  for (int i = tid; i < 2048; i += 256) TWS[i] = tw[i];
  __syncthreads();
  for (int i = tid; i < NSEQ; i += 256) {
    int r = __brev((unsigned)i) >> 20;
    XR[FIDX(r)] = src[i];
  }
  __syncthreads();
  fft4096_core(XR, XI, TWS, false);
  float2* dst = (float2*)fftu + ((size_t)b * NFEAT + f) * KBINS;
  for (int k = tid; k < KBINS; k += 256)
    dst[k] = make_float2(XR[FIDX(k)], XI[FIDX(k)]);
}

// ---------------------------------------------------------------------------
// k3o: fused G+Z for one o-chunk (32 o's), all k.
//   G[o,f,k] = sum_mi Wh_w[o, f*64+mi] * fHd[mi,k]
//   Zc[b,olocal,k] = sum_f fft_u[b,f,k] * G[o,f,k]
// ---------------------------------------------------------------------------
__global__ __launch_bounds__(256) void k3o(
    const float* __restrict__ Whw, const float* __restrict__ fHd,
    const float* __restrict__ fftu, float* __restrict__ Zc, int ob0) {
  __shared__ float2 WhP[4096];
  __shared__ float2 fHc[64][65];
  __shared__ float red[4][64][33];
  const int tid = threadIdx.x;
  const int ol0 = blockIdx.x * 2;          // o_local base (0..30)
  const int o0 = ob0 + ol0;
  const int k0 = blockIdx.y * 64;

  for (int e = tid; e < 4096; e += 256)
    WhP[e] = make_float2(Whw[(size_t)o0 * 4096 + e],
                         Whw[(size_t)(o0 + 1) * 4096 + e]);
  for (int e = tid; e < 4096; e += 256) {
    int mi = e >> 6, kk = e & 63;
    int k = k0 + kk;
    float2 v = make_float2(0.f, 0.f);
    if (k < KBINS) v = ((const float2*)fHd)[(size_t)mi * KBINS + k];
    fHc[mi][kk] = v;
  }
  __syncthreads();

  const int tk = tid & 63, g = tid >> 6;
  const int k = k0 + tk;
  const bool kok = (k < KBINS);
  float zr[2][8], zi[2][8];
#pragma unroll
  for (int ol = 0; ol < 2; ++ol)
#pragma unroll
    for (int b = 0; b < 8; ++b) { zr[ol][b] = 0.f; zi[ol][b] = 0.f; }

  const float2* fu2 = (const float2*)fftu;
  for (int ff = 0; ff < 16; ++ff) {
    const int f = g * 16 + ff;
    float g0r = 0.f, g0i = 0.f, g1r = 0.f, g1i = 0.f;
#pragma unroll 16
    for (int mi = 0; mi < 64; ++mi) {
      float2 h = fHc[mi][tk];
      float2 w = WhP[f * 64 + mi];
      g0r = fmaf(w.x, h.x, g0r); g0i = fmaf(w.x, h.y, g0i);
      g1r = fmaf(w.y, h.x, g1r); g1i = fmaf(w.y, h.y, g1i);
    }
    if (kok) {
#pragma unroll
      for (int b = 0; b < 8; ++b) {
        float2 u = fu2[(size_t)(b * NFEAT + f) * KBINS + k];
        zr[0][b] = fmaf(u.x, g0r, fmaf(-u.y, g0i, zr[0][b]));
        zi[0][b] = fmaf(u.x, g0i, fmaf( u.y, g0r, zi[0][b]));
        zr[1][b] = fmaf(u.x, g1r, fmaf(-u.y, g1i, zr[1][b]));
        zi[1][b] = fmaf(u.x, g1i, fmaf( u.y, g1r, zi[1][b]));
      }
    }
  }
#pragma unroll
  for (int ol = 0; ol < 2; ++ol)
#pragma unroll
    for (int b = 0; b < 8; ++b) {
      red[g][tk][(ol * 8 + b) * 2 + 0] = zr[ol][b];
      red[g][tk][(ol * 8 + b) * 2 + 1] = zi[ol][b];
    }
  __syncthreads();
  if (g == 0 && kok) {
    float2* Z2 = (float2*)Zc;
#pragma unroll
    for (int ol = 0; ol < 2; ++ol)
#pragma unroll
      for (int b = 0; b < 8; ++b) {
        int i0 = (ol * 8 + b) * 2;
        float sr = red[0][tk][i0]     + red[1][tk][i0]
                 + red[2][tk][i0]     + red[3][tk][i0];
        float si = red[0][tk][i0 + 1] + red[1][tk][i0 + 1]
                 + red[2][tk][i0 + 1] + red[3][tk][i0 + 1];
        Z2[((size_t)b * OCH + ol0 + ol) * KBINS + k] = make_float2(sr, si);
      }
  }
}

// ---------------------------------------------------------------------------
// k4f: irfft via LDS FFT; dout[b,o,t] += XR[t]/4096. 1 block per (b,olocal).
// ---------------------------------------------------------------------------
__global__ __launch_bounds__(256) void k4f(
    const float* __restrict__ Zc, const float2* __restrict__ tw,
    float* __restrict__ dout, int ob0) {
  __shared__ float XR[FFT_LDS], XI[FFT_LDS];
  __shared__ float2 TWS[2048];
  const int tid = threadIdx.x;
  const int b = blockIdx.x >> 5, ol = blockIdx.x & 31;
  const int o = ob0 + ol;
  const float2* Z2 = (const float2*)Zc + ((size_t)b * OCH + ol) * KBINS;
  for (int i = tid; i < 2048; i += 256) TWS[i] = tw[i];
  for (int i = tid; i < NFFT; i += 256) {
    float2 v;
    if (i < KBINS) v = Z2[i];
    else { v = Z2[NFFT - i]; v.y = -v.y; }
    int r = __brev((unsigned)i) >> 20;
    XR[FIDX(r)] = v.x; XI[FIDX(r)] = v.y;
  }
  __syncthreads();
  fft4096_core(XR, XI, TWS, true);
  const float inv = 1.0f / (float)NFFT;
  float* drow = dout + ((size_t)b * NHID + o) * NSEQ;
  for (int t = tid; t < NSEQ; t += 256)
    drow[t] += XR[FIDX(t)] * inv;
}

// ---------------------------------------------------------------------------
extern "C" void kernel_launch(void* const* d_in, const int* in_sizes, int n_in,
                              void* d_out, int out_size, void* d_ws, size_t ws_size,
                              hipStream_t stream) {
  const float* x   = (const float*)d_in[0];
  const float* Wuw = (const float*)d_in[1];
  const float* Wub = (const float*)d_in[2];
  const float* Whw = (const float*)d_in[3];
  const float* Whb = (const float*)d_in[4];
  // d_in[5] (fft_H) intentionally UNUSED: recomputed on-device in fp64.
  float* out = (float*)d_out;
  float* ws  = (float*)d_ws;

  float* fftu = ws + FFTU_OFF;
  float* uz   = ws + UZ_OFF;       // f64 W/Mk -> ubuf -> Z o-chunks
  float* fHd  = ws + FHD_OFF;
  float2* tw  = (float2*)(ws + TW_OFF);
  float* Hbuf = ws + HBUF_OFF;
  double* D   = (double*)uz;

  k0_tw<<<8, 256, 0, stream>>>(tw);
  kA2_expm<<<1, KA_NT, 3 * 4225 * sizeof(double), stream>>>(D);
  kB_cols<<<32, 256, 0, stream>>>(D, Hbuf);
  kC_fft<<<NMEM, 256, 0, stream>>>(Hbuf, tw, fHd);
  k1t<<<dim3(NSEQ / 128, NOUTCH / 64, NB), 256, 0, stream>>>(x, Wuw, Wub, Whb, out, uz);
  k2f<<<NB * NFEAT, 256, 0, stream>>>(uz, tw, fftu);
  for (int oc = 0; oc < NOCH; ++oc) {
    int ob0 = oc * OCH;
    k3o<<<dim3(OCH / 2, (KBINS + 63) / 64), 256, 0, stream>>>(Whw, fHd, fftu, uz, ob0);
    k4f<<<NB * OCH, 256, 0, stream>>>(uz, tw, out, ob0);
  }
}

// Round 10
// 6612.189 us; speedup vs baseline: 1.1824x; 1.1824x over previous
//
#include <hip/hip_runtime.h>
#include <hip/hip_bf16.h>
#include <math.h>

// Problem constants
#define NB 8
#define NIN 256
#define NHID 256
#define NMEM 64
#define NSEQ 2048
#define NFEAT 64
#define NOUTCH 320        // NFEAT + NHID
#define NFFT 4096
#define KBINS 2049        // NSEQ + 1
#define OCH 32            // o-chunk size
#define NOCH 8            // 256 / 32

// ws layout (float offsets) — TOTAL 14.18 MB (within round-7 proven budget)
#define FFTU_OFF 0
#define FFTU_SZ (NB * NFEAT * KBINS * 2)               // 2,098,176 (8.4 MB)
#define UZ_OFF (FFTU_OFF + FFTU_SZ)                    // overlay: f64 W/Mk -> ubuf -> Z o-chunks
#define UZ_SZ (NB * OCH * KBINS * 2)                   // 1,049,088 (4.2 MB)
#define FHD_OFF (UZ_OFF + UZ_SZ)
#define FHD_SZ (NMEM * KBINS * 2)                      // 262,272 (1.05 MB)
#define TW_OFF (FHD_OFF + FHD_SZ)
#define TW_SZ (2048 * 2)                               // 16 KB
#define HBUF_OFF (TW_OFF + TW_SZ)
#define HBUF_SZ (NMEM * NSEQ)                          // 131,072 (0.52 MB)

// f64 outputs of kA (doubles, based at UZ_OFF; dead before ubuf is written)
#define DW_OFF   0        // [64 r][64 j] = Ad^r Bd
#define DMK_OFF  4096     // [32 k][64][64] = (Ad^64)^k

// padded LDS index for FFT arrays (breaks power-of-2 stride bank conflicts)
#define FIDX(i) ((i) + ((i) >> 5) + ((i) >> 10))
#define FFT_LDS 4240

// ---------------------------------------------------------------------------
// shared 4096-pt radix-2 DIT core (data already bit-reversed into XR/XI)
// ---------------------------------------------------------------------------
__device__ __forceinline__ void fft4096_core(float* XR, float* XI,
                                             const float2* TWS, bool inverse) {
#pragma unroll 1
  for (int s = 1; s <= 12; ++s) {
    int half = 1 << (s - 1);
    int shift = 12 - s;
#pragma unroll
    for (int q = 0; q < 8; ++q) {
      int bf = threadIdx.x + q * 256;
      int j = bf & (half - 1);
      int base = ((bf >> (s - 1)) << s) + j;
      float2 w = TWS[j << shift];
      float wr = w.x, wi = inverse ? -w.y : w.y;
      int i0 = FIDX(base), i1 = FIDX(base + half);
      float ar = XR[i0], ai = XI[i0];
      float br = XR[i1], bi = XI[i1];
      float tr = wr * br - wi * bi, ti = wr * bi + wi * br;
      XR[i0] = ar + tr; XI[i0] = ai + ti;
      XR[i1] = ar - tr; XI[i1] = ai - ti;
    }
    __syncthreads();
  }
}

// ---------------------------------------------------------------------------
// k0: tw[m] = exp(-2*pi*i*m/4096), m in [0,2048), double precision.
// ---------------------------------------------------------------------------
__global__ void k0_tw(float2* __restrict__ tw) {
  int m = blockIdx.x * 256 + threadIdx.x;
  if (m < 2048) {
    double ang = -2.0 * 3.14159265358979323846 * (double)m / 4096.0;
    tw[m] = make_float2((float)cos(ang), (float)sin(ang));
  }
}

// ---------------------------------------------------------------------------
// kA3: LDS-resident fp64 discretization.
// Round-9 post-mortem: 1024 thr => 64-VGPR cap => fp64 staging spilled to
// scratch (118 MB writes, 6.8 ms). Now 256 thr + __launch_bounds__(256,1)
// (1 wave/SIMD => up to 512 VGPR): tn[17]/tn[16] staging stays in registers.
//  1) blk=[[A,B],[0,0]] (65x65); Taylor expm (29 terms, s squarings);
//     Ad,Bd rounded through f32 (as reference).
//  2) W[r]=Ad^r Bd (r<64); Ad64=Ad^64 (6 squarings); Mk[k]=(Ad64)^k (k<32).
// Outputs only W, Mk to global (for kB).
// ---------------------------------------------------------------------------
#define KA_NT 256
__global__ __launch_bounds__(KA_NT, 1) void kA3_expm(double* __restrict__ D) {
  extern __shared__ double lds[];
  double* Msh = lds;           // 4225
  double* Tsh = lds + 4225;    // 4225
  double* Esh = lds + 8450;    // 4225
  __shared__ double sh_scale;
  __shared__ int sh_s;
  const int tid = threadIdx.x;

  // 1) build blk matrix
  for (int e = tid; e < 4225; e += KA_NT) {
    int i = e / 65, j = e % 65;
    double val = 0.0;
    if (i < 64) {
      double R = (2.0 * i + 1.0) / 2048.0;
      if (j < 64) val = R * ((i < j) ? -1.0 : (((i - j) & 1) ? 1.0 : -1.0));
      else        val = R * ((i & 1) ? -1.0 : 1.0);   // Bc = R*(-1)^i
    }
    Msh[e] = val;
  }
  __syncthreads();
  // norm-1 (max column abs-sum)
  if (tid < 65) {
    double cs = 0.0;
    for (int i = 0; i < 65; ++i) cs += fabs(Msh[i * 65 + tid]);
    Tsh[tid] = cs;
  }
  __syncthreads();
  if (tid == 0) {
    double norm = 0.0;
    for (int j = 0; j < 65; ++j) if (Tsh[j] > norm) norm = Tsh[j];
    if (norm < 1e-16) norm = 1e-16;
    int s = (int)ceil(log2(norm)) + 1;
    if (s < 0) s = 0;
    sh_s = s;
    double sc = 1.0;
    for (int q = 0; q < s; ++q) sc *= 0.5;
    sh_scale = sc;
  }
  __syncthreads();
  const double scale = sh_scale;
  const int s = sh_s;
  for (int e = tid; e < 4225; e += KA_NT) {
    int i = e / 65, j = e % 65;
    Msh[e] *= scale;
    double id = (i == j) ? 1.0 : 0.0;
    Tsh[e] = id; Esh[e] = id;
  }
  __syncthreads();

  // 2) Taylor: T = T@M/k; E += T   (29 terms); 17*256 >= 4225
  for (int k = 1; k <= 29; ++k) {
    double tn[17];
#pragma unroll
    for (int r = 0; r < 17; ++r) {
      int e = tid + r * KA_NT;
      double dot = 0.0;
      if (e < 4225) {
        int i = e / 65, j = e % 65;
        for (int l = 0; l < 65; ++l) dot += Tsh[i * 65 + l] * Msh[l * 65 + j];
        dot /= (double)k;
      }
      tn[r] = dot;
    }
    __syncthreads();
#pragma unroll
    for (int r = 0; r < 17; ++r) {
      int e = tid + r * KA_NT;
      if (e < 4225) { Tsh[e] = tn[r]; Esh[e] += tn[r]; }
    }
    __syncthreads();
  }
  // 3) s squarings: E = E@E
  for (int q = 0; q < s; ++q) {
    double tn[17];
#pragma unroll
    for (int r = 0; r < 17; ++r) {
      int e = tid + r * KA_NT;
      double dot = 0.0;
      if (e < 4225) {
        int i = e / 65, j = e % 65;
        for (int l = 0; l < 65; ++l) dot += Esh[i * 65 + l] * Esh[l * 65 + j];
      }
      tn[r] = dot;
    }
    __syncthreads();
#pragma unroll
    for (int r = 0; r < 17; ++r) {
      int e = tid + r * KA_NT;
      if (e < 4225) Esh[e] = tn[r];
    }
    __syncthreads();
  }
  // 4) extract Ad (f32-rounded) into Msh, Bd into Tsh[0..63]; 16*256 = 4096
  {
    double ad[16];
#pragma unroll
    for (int r = 0; r < 16; ++r) {
      int e = tid + r * KA_NT;
      ad[r] = (double)(float)Esh[(e >> 6) * 65 + (e & 63)];
    }
    double bd = (tid < 64) ? (double)(float)Esh[tid * 65 + 64] : 0.0;
    __syncthreads();
#pragma unroll
    for (int r = 0; r < 16; ++r) { int e = tid + r * KA_NT; Msh[e] = ad[r]; }
    if (tid < 64) Tsh[tid] = bd;
    __syncthreads();
  }
  // 5) W chain in Esh: W[r] = Ad^r Bd
  if (tid < 64) Esh[tid] = Tsh[tid];
  __syncthreads();
  for (int r = 1; r < 64; ++r) {
    double dot = 0.0;
    if (tid < 64) {
      for (int j = 0; j < 64; ++j)
        dot += Msh[tid * 64 + j] * Esh[(r - 1) * 64 + j];
    }
    __syncthreads();
    if (tid < 64) Esh[r * 64 + tid] = dot;
    __syncthreads();
  }
  for (int e = tid; e < 4096; e += KA_NT) D[DW_OFF + e] = Esh[e];
  // 6) Ad64 = Ad^64: Tsh <- Ad, 6 squarings
  for (int e = tid; e < 4096; e += KA_NT) Tsh[e] = Msh[e];
  __syncthreads();
  for (int q = 0; q < 6; ++q) {
    double tn[16];
#pragma unroll
    for (int r = 0; r < 16; ++r) {
      int e = tid + r * KA_NT;
      int i = e >> 6, j = e & 63;
      double dot = 0.0;
      for (int l = 0; l < 64; ++l) dot += Tsh[i * 64 + l] * Tsh[l * 64 + j];
      tn[r] = dot;
    }
    __syncthreads();
#pragma unroll
    for (int r = 0; r < 16; ++r) { int e = tid + r * KA_NT; Tsh[e] = tn[r]; }
    __syncthreads();
  }
  // 7) Mk chain in Esh (W already flushed): Mk[0]=I; Mk[k]=Mk[k-1]@Ad64
  for (int e = tid; e < 4096; e += KA_NT) {
    double id = ((e >> 6) == (e & 63)) ? 1.0 : 0.0;
    Esh[e] = id;
    D[DMK_OFF + e] = id;
  }
  __syncthreads();
  for (int k = 1; k < 32; ++k) {
    double tn[16];
#pragma unroll
    for (int r = 0; r < 16; ++r) {
      int e = tid + r * KA_NT;
      int i = e >> 6, j = e & 63;
      double dot = 0.0;
      for (int l = 0; l < 64; ++l) dot += Esh[i * 64 + l] * Tsh[l * 64 + j];
      tn[r] = dot;
    }
    __syncthreads();
#pragma unroll
    for (int r = 0; r < 16; ++r) {
      int e = tid + r * KA_NT;
      Esh[e] = tn[r];
      D[DMK_OFF + (size_t)k * 4096 + e] = tn[r];
    }
    __syncthreads();
  }
}

// ---------------------------------------------------------------------------
// kB: parallel impulse response. Block k (of 32): H[i, 64k+r] = Mk[k] @ W[r].
// ---------------------------------------------------------------------------
__global__ __launch_bounds__(256) void kB_cols(const double* __restrict__ D,
                                               float* __restrict__ H) {
  const double* W = D + DW_OFF;
  const double* Mrow = D + DMK_OFF + (size_t)blockIdx.x * 4096;
  __shared__ double Ms[4096];
  const int tid = threadIdx.x;
  for (int e = tid; e < 4096; e += 256) Ms[e] = Mrow[e];
  __syncthreads();
  const int c0 = blockIdx.x * 64;
  for (int e = tid; e < 4096; e += 256) {
    int i = e >> 6, r = e & 63;
    double dot = 0.0;
#pragma unroll 16
    for (int j = 0; j < 64; ++j) dot += Ms[i * 64 + j] * W[r * 64 + j];
    H[(size_t)i * NSEQ + c0 + r] = (float)dot;
  }
}

// ---------------------------------------------------------------------------
// kC: fHd[mi,k] = rfft(H[mi,:], n=4096)[k] via LDS FFT. 1 block/row.
// ---------------------------------------------------------------------------
__global__ __launch_bounds__(256) void kC_fft(const float* __restrict__ H,
                                              const float2* __restrict__ tw,
                                              float* __restrict__ fHd) {
  __shared__ float XR[FFT_LDS], XI[FFT_LDS];
  __shared__ float2 TWS[2048];
  const int tid = threadIdx.x;
  const int mi = blockIdx.x;
  const float* src = H + (size_t)mi * NSEQ;
  for (int i = tid; i < NFFT; i += 256) { XR[FIDX(i)] = 0.f; XI[FIDX(i)] = 0.f; }
  for (int i = tid; i < 2048; i += 256) TWS[i] = tw[i];
  __syncthreads();
  for (int i = tid; i < NSEQ; i += 256) {
    int r = __brev((unsigned)i) >> 20;
    XR[FIDX(r)] = src[i];
  }
  __syncthreads();
  fft4096_core(XR, XI, TWS, false);
  float2* dst = (float2*)fHd + (size_t)mi * KBINS;
  for (int k = tid; k < KBINS; k += 256)
    dst[k] = make_float2(XR[FIDX(k)], XI[FIDX(k)]);
}

// ---------------------------------------------------------------------------
// k1t: tiled GEMM out[b,o,s] = bias + sum_i Wu_w[o,i]*x[b,i,s]
//   o<256 -> dout = acc + Wu_b + Wh_b ; o>=256 -> ubuf = relu(acc + Wu_b)
// ---------------------------------------------------------------------------
__global__ __launch_bounds__(256) void k1t(
    const float* __restrict__ x, const float* __restrict__ Wuw,
    const float* __restrict__ Wub, const float* __restrict__ Whb,
    float* __restrict__ dout, float* __restrict__ ubuf) {
  __shared__ float xs[32][128];
  __shared__ float wsh[32][68];
  const int tid = threadIdx.x;
  const int b = blockIdx.z;
  const int o0 = blockIdx.y * 64;
  const int s0 = blockIdx.x * 128;
  const int sx = tid & 15, oy = tid >> 4;
  float acc[4][8];
#pragma unroll
  for (int j = 0; j < 4; ++j)
#pragma unroll
    for (int l = 0; l < 8; ++l) acc[j][l] = 0.f;

  for (int i0 = 0; i0 < 256; i0 += 32) {
#pragma unroll
    for (int e4 = tid; e4 < 1024; e4 += 256) {
      int ii = e4 >> 5, ss4 = (e4 & 31) << 2;
      float4 v = *(const float4*)&x[(size_t)(b * NIN + i0 + ii) * NSEQ + s0 + ss4];
      *(float4*)&xs[ii][ss4] = v;
    }
#pragma unroll
    for (int e4 = tid; e4 < 512; e4 += 256) {
      int oj = e4 >> 3, ii4 = (e4 & 7) << 2;
      float4 v = *(const float4*)&Wuw[(o0 + oj) * NIN + i0 + ii4];
      wsh[ii4][oj] = v.x; wsh[ii4 + 1][oj] = v.y;
      wsh[ii4 + 2][oj] = v.z; wsh[ii4 + 3][oj] = v.w;
    }
    __syncthreads();
#pragma unroll 8
    for (int kk = 0; kk < 32; ++kk) {
      float4 a = *(const float4*)&wsh[kk][oy * 4];
      float4 b0 = *(const float4*)&xs[kk][sx * 4];
      float4 b1 = *(const float4*)&xs[kk][64 + sx * 4];
      float av[4] = {a.x, a.y, a.z, a.w};
      float bv[8] = {b0.x, b0.y, b0.z, b0.w, b1.x, b1.y, b1.z, b1.w};
#pragma unroll
      for (int j = 0; j < 4; ++j)
#pragma unroll
        for (int l = 0; l < 8; ++l) acc[j][l] = fmaf(av[j], bv[l], acc[j][l]);
    }
    __syncthreads();
  }
#pragma unroll
  for (int j = 0; j < 4; ++j) {
    int o = o0 + oy * 4 + j;
    if (o < NHID) {
      float bias = Wub[o] + Whb[o];
      size_t base = ((size_t)b * NHID + o) * NSEQ + s0;
      float4 v0 = make_float4(acc[j][0] + bias, acc[j][1] + bias,
                              acc[j][2] + bias, acc[j][3] + bias);
      float4 v1 = make_float4(acc[j][4] + bias, acc[j][5] + bias,
                              acc[j][6] + bias, acc[j][7] + bias);
      *(float4*)&dout[base + sx * 4] = v0;
      *(float4*)&dout[base + 64 + sx * 4] = v1;
    } else {
      float bias = Wub[o];
      size_t base = ((size_t)b * NFEAT + (o - NHID)) * NSEQ + s0;
      float4 v0 = make_float4(fmaxf(acc[j][0] + bias, 0.f), fmaxf(acc[j][1] + bias, 0.f),
                              fmaxf(acc[j][2] + bias, 0.f), fmaxf(acc[j][3] + bias, 0.f));
      float4 v1 = make_float4(fmaxf(acc[j][4] + bias, 0.f), fmaxf(acc[j][5] + bias, 0.f),
                              fmaxf(acc[j][6] + bias, 0.f), fmaxf(acc[j][7] + bias, 0.f));
      *(float4*)&ubuf[base + sx * 4] = v0;
      *(float4*)&ubuf[base + 64 + sx * 4] = v1;
    }
  }
}

// ---------------------------------------------------------------------------
// k2f: fft_u[b,f,k] = rfft(ubuf[b,f,:], n=4096)[k] via LDS FFT. 1 block/row.
// ---------------------------------------------------------------------------
__global__ __launch_bounds__(256) void k2f(
    const float* __restrict__ ubuf, const float2* __restrict__ tw,
    float* __restrict__ fftu) {
  __shared__ float XR[FFT_LDS], XI[FFT_LDS];
  __shared__ float2 TWS[2048];
  const int tid = threadIdx.x;
  const int b = blockIdx.x >> 6, f = blockIdx.x & 63;
  const float* src = ubuf + ((size_t)b * NFEAT + f) * NSEQ;
  for (int i = tid; i < NFFT; i += 256) { XR[FIDX(i)] = 0.f; XI[FIDX(i)] = 0.f; }
  for (int i = tid; i < 2048; i += 256) TWS[i] = tw[i];
  __syncthreads();
  for (int i = tid; i < NSEQ; i += 256) {
    int r = __brev((unsigned)i) >> 20;
    XR[FIDX(r)] = src[i];
  }
  __syncthreads();
  fft4096_core(XR, XI, TWS, false);
  float2* dst = (float2*)fftu + ((size_t)b * NFEAT + f) * KBINS;
  for (int k = tid; k < KBINS; k += 256)
    dst[k] = make_float2(XR[FIDX(k)], XI[FIDX(k)]);
}

// ---------------------------------------------------------------------------
// k3o: fused G+Z for one o-chunk (32 o's), all k.
//   G[o,f,k] = sum_mi Wh_w[o, f*64+mi] * fHd[mi,k]
//   Zc[b,olocal,k] = sum_f fft_u[b,f,k] * G[o,f,k]
// ---------------------------------------------------------------------------
__global__ __launch_bounds__(256) void k3o(
    const float* __restrict__ Whw, const float* __restrict__ fHd,
    const float* __restrict__ fftu, float* __restrict__ Zc, int ob0) {
  __shared__ float2 WhP[4096];
  __shared__ float2 fHc[64][65];
  __shared__ float red[4][64][33];
  const int tid = threadIdx.x;
  const int ol0 = blockIdx.x * 2;          // o_local base (0..30)
  const int o0 = ob0 + ol0;
  const int k0 = blockIdx.y * 64;

  for (int e = tid; e < 4096; e += 256)
    WhP[e] = make_float2(Whw[(size_t)o0 * 4096 + e],
                         Whw[(size_t)(o0 + 1) * 4096 + e]);
  for (int e = tid; e < 4096; e += 256) {
    int mi = e >> 6, kk = e & 63;
    int k = k0 + kk;
    float2 v = make_float2(0.f, 0.f);
    if (k < KBINS) v = ((const float2*)fHd)[(size_t)mi * KBINS + k];
    fHc[mi][kk] = v;
  }
  __syncthreads();

  const int tk = tid & 63, g = tid >> 6;
  const int k = k0 + tk;
  const bool kok = (k < KBINS);
  float zr[2][8], zi[2][8];
#pragma unroll
  for (int ol = 0; ol < 2; ++ol)
#pragma unroll
    for (int b = 0; b < 8; ++b) { zr[ol][b] = 0.f; zi[ol][b] = 0.f; }

  const float2* fu2 = (const float2*)fftu;
  for (int ff = 0; ff < 16; ++ff) {
    const int f = g * 16 + ff;
    float g0r = 0.f, g0i = 0.f, g1r = 0.f, g1i = 0.f;
#pragma unroll 16
    for (int mi = 0; mi < 64; ++mi) {
      float2 h = fHc[mi][tk];
      float2 w = WhP[f * 64 + mi];
      g0r = fmaf(w.x, h.x, g0r); g0i = fmaf(w.x, h.y, g0i);
      g1r = fmaf(w.y, h.x, g1r); g1i = fmaf(w.y, h.y, g1i);
    }
    if (kok) {
#pragma unroll
      for (int b = 0; b < 8; ++b) {
        float2 u = fu2[(size_t)(b * NFEAT + f) * KBINS + k];
        zr[0][b] = fmaf(u.x, g0r, fmaf(-u.y, g0i, zr[0][b]));
        zi[0][b] = fmaf(u.x, g0i, fmaf( u.y, g0r, zi[0][b]));
        zr[1][b] = fmaf(u.x, g1r, fmaf(-u.y, g1i, zr[1][b]));
        zi[1][b] = fmaf(u.x, g1i, fmaf( u.y, g1r, zi[1][b]));
      }
    }
  }
#pragma unroll
  for (int ol = 0; ol < 2; ++ol)
#pragma unroll
    for (int b = 0; b < 8; ++b) {
      red[g][tk][(ol * 8 + b) * 2 + 0] = zr[ol][b];
      red[g][tk][(ol * 8 + b) * 2 + 1] = zi[ol][b];
    }
  __syncthreads();
  if (g == 0 && kok) {
    float2* Z2 = (float2*)Zc;
#pragma unroll
    for (int ol = 0; ol < 2; ++ol)
#pragma unroll
      for (int b = 0; b < 8; ++b) {
        int i0 = (ol * 8 + b) * 2;
        float sr = red[0][tk][i0]     + red[1][tk][i0]
                 + red[2][tk][i0]     + red[3][tk][i0];
        float si = red[0][tk][i0 + 1] + red[1][tk][i0 + 1]
                 + red[2][tk][i0 + 1] + red[3][tk][i0 + 1];
        Z2[((size_t)b * OCH + ol0 + ol) * KBINS + k] = make_float2(sr, si);
      }
  }
}

// ---------------------------------------------------------------------------
// k4f: irfft via LDS FFT; dout[b,o,t] += XR[t]/4096. 1 block per (b,olocal).
// ---------------------------------------------------------------------------
__global__ __launch_bounds__(256) void k4f(
    const float* __restrict__ Zc, const float2* __restrict__ tw,
    float* __restrict__ dout, int ob0) {
  __shared__ float XR[FFT_LDS], XI[FFT_LDS];
  __shared__ float2 TWS[2048];
  const int tid = threadIdx.x;
  const int b = blockIdx.x >> 5, ol = blockIdx.x & 31;
  const int o = ob0 + ol;
  const float2* Z2 = (const float2*)Zc + ((size_t)b * OCH + ol) * KBINS;
  for (int i = tid; i < 2048; i += 256) TWS[i] = tw[i];
  for (int i = tid; i < NFFT; i += 256) {
    float2 v;
    if (i < KBINS) v = Z2[i];
    else { v = Z2[NFFT - i]; v.y = -v.y; }
    int r = __brev((unsigned)i) >> 20;
    XR[FIDX(r)] = v.x; XI[FIDX(r)] = v.y;
  }
  __syncthreads();
  fft4096_core(XR, XI, TWS, true);
  const float inv = 1.0f / (float)NFFT;
  float* drow = dout + ((size_t)b * NHID + o) * NSEQ;
  for (int t = tid; t < NSEQ; t += 256)
    drow[t] += XR[FIDX(t)] * inv;
}

// ---------------------------------------------------------------------------
extern "C" void kernel_launch(void* const* d_in, const int* in_sizes, int n_in,
                              void* d_out, int out_size, void* d_ws, size_t ws_size,
                              hipStream_t stream) {
  const float* x   = (const float*)d_in[0];
  const float* Wuw = (const float*)d_in[1];
  const float* Wub = (const float*)d_in[2];
  const float* Whw = (const float*)d_in[3];
  const float* Whb = (const float*)d_in[4];
  // d_in[5] (fft_H) intentionally UNUSED: recomputed on-device in fp64.
  float* out = (float*)d_out;
  float* ws  = (float*)d_ws;

  float* fftu = ws + FFTU_OFF;
  float* uz   = ws + UZ_OFF;       // f64 W/Mk -> ubuf -> Z o-chunks
  float* fHd  = ws + FHD_OFF;
  float2* tw  = (float2*)(ws + TW_OFF);
  float* Hbuf = ws + HBUF_OFF;
  double* D   = (double*)uz;

  k0_tw<<<8, 256, 0, stream>>>(tw);
  kA3_expm<<<1, KA_NT, 3 * 4225 * sizeof(double), stream>>>(D);
  kB_cols<<<32, 256, 0, stream>>>(D, Hbuf);
  kC_fft<<<NMEM, 256, 0, stream>>>(Hbuf, tw, fHd);
  k1t<<<dim3(NSEQ / 128, NOUTCH / 64, NB), 256, 0, stream>>>(x, Wuw, Wub, Whb, out, uz);
  k2f<<<NB * NFEAT, 256, 0, stream>>>(uz, tw, fftu);
  for (int oc = 0; oc < NOCH; ++oc) {
    int ob0 = oc * OCH;
    k3o<<<dim3(OCH / 2, (KBINS + 63) / 64), 256, 0, stream>>>(Whw, fHd, fftu, uz, ob0);
    k4f<<<NB * OCH, 256, 0, stream>>>(uz, tw, out, ob0);
  }
}

// Round 11
// 1227.578 us; speedup vs baseline: 6.3689x; 5.3864x over previous
//
#include <hip/hip_runtime.h>
#include <hip/hip_bf16.h>
#include <math.h>

// Problem constants
#define NB 8
#define NIN 256
#define NHID 256
#define NMEM 64
#define NSEQ 2048
#define NFEAT 64
#define NOUTCH 320        // NFEAT + NHID
#define NFFT 4096
#define KBINS 2049        // NSEQ + 1
#define OCH 32            // o-chunk size
#define NOCH 8            // 256 / 32

// ws layout (float offsets) — TOTAL 14.18 MB
#define FFTU_OFF 0
#define FFTU_SZ (NB * NFEAT * KBINS * 2)               // 2,098,176 (8.4 MB)
#define UZ_OFF (FFTU_OFF + FFTU_SZ)                    // overlay: f64 scratch -> ubuf -> Z o-chunks
#define UZ_SZ (NB * OCH * KBINS * 2)                   // 1,049,088 (4.2 MB)
#define FHD_OFF (UZ_OFF + UZ_SZ)
#define FHD_SZ (NMEM * KBINS * 2)                      // 262,272 (1.05 MB)
#define TW_OFF (FHD_OFF + FHD_SZ)
#define TW_SZ (2048 * 2)                               // 16 KB
#define HBUF_OFF (TW_OFF + TW_SZ)
#define HBUF_SZ (NMEM * NSEQ)                          // 131,072 (0.52 MB)

// f64 scratch layout (doubles, based at UZ_OFF; dead before ubuf is written)
// total 180,869 doubles = 1.45 MB — L2-resident working set ~135 KB/phase
#define DMM   0                      // 65x65 scaled blk
#define DTT0  4225                   // Taylor T ping
#define DTT1  8450                   // Taylor T pong
#define DEE0  12675                  // E ping
#define DEE1  16900                  // E pong
#define DPW   21125                  // pw[0..5] = Ad^(2^m), 6*4096
#define DWV   (DPW + 6 * 4096)       // 45701: W[r][j] = (Ad^r Bd)[j], 64x64
#define DMK2  (DWV + 4096)           // 49797: Mk[k] = (Ad^64)^k, 32*4096

// padded LDS index for FFT arrays (breaks power-of-2 stride bank conflicts)
#define FIDX(i) ((i) + ((i) >> 5) + ((i) >> 10))
#define FFT_LDS 4240

// ---------------------------------------------------------------------------
// shared 4096-pt radix-2 DIT core (data already bit-reversed into XR/XI)
// ---------------------------------------------------------------------------
__device__ __forceinline__ void fft4096_core(float* XR, float* XI,
                                             const float2* TWS, bool inverse) {
#pragma unroll 1
  for (int s = 1; s <= 12; ++s) {
    int half = 1 << (s - 1);
    int shift = 12 - s;
#pragma unroll
    for (int q = 0; q < 8; ++q) {
      int bf = threadIdx.x + q * 256;
      int j = bf & (half - 1);
      int base = ((bf >> (s - 1)) << s) + j;
      float2 w = TWS[j << shift];
      float wr = w.x, wi = inverse ? -w.y : w.y;
      int i0 = FIDX(base), i1 = FIDX(base + half);
      float ar = XR[i0], ai = XI[i0];
      float br = XR[i1], bi = XI[i1];
      float tr = wr * br - wi * bi, ti = wr * bi + wi * br;
      XR[i0] = ar + tr; XI[i0] = ai + ti;
      XR[i1] = ar - tr; XI[i1] = ai - ti;
    }
    __syncthreads();
  }
}

// ---------------------------------------------------------------------------
// k0: tw[m] = exp(-2*pi*i*m/4096), m in [0,2048), double precision.
// ---------------------------------------------------------------------------
__global__ void k0_tw(float2* __restrict__ tw) {
  int m = blockIdx.x * 256 + threadIdx.x;
  if (m < 2048) {
    double ang = -2.0 * 3.14159265358979323846 * (double)m / 4096.0;
    tw[m] = make_float2((float)cos(ang), (float)sin(ang));
  }
}

// ---------------------------------------------------------------------------
// kA chain (round-10 post-mortem: single-kernel fp64 ran on ONE CU and
// spilled 92 MB of scratch at 17 GB/s => 5.7 ms). Now ~54 tiny L2-resident
// matmul launches, each ~10 VGPR, multi-block, graph-captured in order.
// norm1(blk) == 2.0 exactly (cols sum to sum(2i+1)/2048 = 2) => s=2, scale=.25.
// ---------------------------------------------------------------------------
// build M = 0.25 * blk  (65x65)
__global__ __launch_bounds__(256) void kblk(double* __restrict__ M) {
  int e = blockIdx.x * 256 + threadIdx.x;
  if (e < 4225) {
    int i = e / 65, j = e % 65;
    double val = 0.0;
    if (i < 64) {
      double R = (2.0 * i + 1.0) / 2048.0;
      if (j < 64) val = R * ((i < j) ? -1.0 : (((i - j) & 1) ? 1.0 : -1.0));
      else        val = R * ((i & 1) ? -1.0 : 1.0);   // Bc = R*(-1)^i
    }
    M[e] = 0.25 * val;
  }
}
// T = E = I
__global__ __launch_bounds__(256) void kinitTE(double* __restrict__ T,
                                               double* __restrict__ E) {
  int e = blockIdx.x * 256 + threadIdx.x;
  if (e < 4225) {
    double id = ((e / 65) == (e % 65)) ? 1.0 : 0.0;
    T[e] = id; E[e] = id;
  }
}
// C = (A @ B) / kd ; if E: E += C      (65x65, grid 17)
__global__ __launch_bounds__(256) void kmm65(const double* __restrict__ A,
                                             const double* __restrict__ B,
                                             double* __restrict__ C,
                                             double* __restrict__ E, double kd) {
  int e = blockIdx.x * 256 + threadIdx.x;
  if (e >= 4225) return;
  int i = e / 65, j = e % 65;
  const double* ar = A + i * 65;
  double dot = 0.0;
  for (int l = 0; l < 65; ++l) dot += ar[l] * B[l * 65 + j];
  dot /= kd;
  C[e] = dot;
  if (E) E[e] += dot;
}
// extract Ad (f32-rounded) -> pw[0]; Bd -> W[0]; Mk[0] = I
__global__ __launch_bounds__(256) void kext(const double* __restrict__ E,
                                            double* __restrict__ D) {
  int e = blockIdx.x * 256 + threadIdx.x;
  if (e < 4096) {
    int i = e >> 6, j = e & 63;
    D[DPW + e] = (double)(float)E[i * 65 + j];
    D[DMK2 + e] = (i == j) ? 1.0 : 0.0;
  } else if (e < 4160) {
    int j = e - 4096;
    D[DWV + j] = (double)(float)E[j * 65 + 64];
  }
}
// C = A @ B   (64x64, grid 16)
__global__ __launch_bounds__(256) void kmm64(const double* __restrict__ A,
                                             const double* __restrict__ B,
                                             double* __restrict__ C) {
  int e = blockIdx.x * 256 + threadIdx.x;
  int i = e >> 6, j = e & 63;
  double dot = 0.0;
  for (int l = 0; l < 64; ++l) dot += A[i * 64 + l] * B[l * 64 + j];
  C[e] = dot;
}
// W level: W[b0+t] = P @ W[t], t in [0,b0)   (vectors; 1 block)
__global__ __launch_bounds__(256) void kwlev(const double* __restrict__ P,
                                             double* __restrict__ W, int b0) {
  int tot = 64 * b0;
  for (int e = threadIdx.x; e < tot; e += 256) {
    int t = e >> 6, i = e & 63;
    double dot = 0.0;
    for (int l = 0; l < 64; ++l) dot += P[i * 64 + l] * W[t * 64 + l];
    W[(size_t)(b0 + t) * 64 + i] = dot;
  }
}
// Mk batch: Out[t] = Q @ Src[t]  (grid (16, count))
__global__ __launch_bounds__(256) void kmk(const double* __restrict__ Q,
                                           const double* __restrict__ Src,
                                           double* __restrict__ Out) {
  int t = blockIdx.y;
  int e = blockIdx.x * 256 + threadIdx.x;
  int i = e >> 6, j = e & 63;
  const double* B = Src + (size_t)t * 4096;
  double dot = 0.0;
  for (int l = 0; l < 64; ++l) dot += Q[i * 64 + l] * B[l * 64 + j];
  Out[(size_t)t * 4096 + e] = dot;
}

// ---------------------------------------------------------------------------
// kB: parallel impulse response. Block k (of 32): H[i, 64k+r] = Mk[k] @ W[r].
// ---------------------------------------------------------------------------
__global__ __launch_bounds__(256) void kB_cols(const double* __restrict__ D,
                                               float* __restrict__ H) {
  const double* W = D + DWV;
  const double* Mrow = D + DMK2 + (size_t)blockIdx.x * 4096;
  __shared__ double Ms[4096];
  const int tid = threadIdx.x;
  for (int e = tid; e < 4096; e += 256) Ms[e] = Mrow[e];
  __syncthreads();
  const int c0 = blockIdx.x * 64;
  for (int e = tid; e < 4096; e += 256) {
    int i = e >> 6, r = e & 63;
    double dot = 0.0;
#pragma unroll 16
    for (int j = 0; j < 64; ++j) dot += Ms[i * 64 + j] * W[r * 64 + j];
    H[(size_t)i * NSEQ + c0 + r] = (float)dot;
  }
}

// ---------------------------------------------------------------------------
// kC: fHd[mi,k] = rfft(H[mi,:], n=4096)[k] via LDS FFT. 1 block/row.
// ---------------------------------------------------------------------------
__global__ __launch_bounds__(256) void kC_fft(const float* __restrict__ H,
                                              const float2* __restrict__ tw,
                                              float* __restrict__ fHd) {
  __shared__ float XR[FFT_LDS], XI[FFT_LDS];
  __shared__ float2 TWS[2048];
  const int tid = threadIdx.x;
  const int mi = blockIdx.x;
  const float* src = H + (size_t)mi * NSEQ;
  for (int i = tid; i < NFFT; i += 256) { XR[FIDX(i)] = 0.f; XI[FIDX(i)] = 0.f; }
  for (int i = tid; i < 2048; i += 256) TWS[i] = tw[i];
  __syncthreads();
  for (int i = tid; i < NSEQ; i += 256) {
    int r = __brev((unsigned)i) >> 20;
    XR[FIDX(r)] = src[i];
  }
  __syncthreads();
  fft4096_core(XR, XI, TWS, false);
  float2* dst = (float2*)fHd + (size_t)mi * KBINS;
  for (int k = tid; k < KBINS; k += 256)
    dst[k] = make_float2(XR[FIDX(k)], XI[FIDX(k)]);
}

// ---------------------------------------------------------------------------
// k1t: tiled GEMM out[b,o,s] = bias + sum_i Wu_w[o,i]*x[b,i,s]
//   o<256 -> dout = acc + Wu_b + Wh_b ; o>=256 -> ubuf = relu(acc + Wu_b)
// ---------------------------------------------------------------------------
__global__ __launch_bounds__(256) void k1t(
    const float* __restrict__ x, const float* __restrict__ Wuw,
    const float* __restrict__ Wub, const float* __restrict__ Whb,
    float* __restrict__ dout, float* __restrict__ ubuf) {
  __shared__ float xs[32][128];
  __shared__ float wsh[32][68];
  const int tid = threadIdx.x;
  const int b = blockIdx.z;
  const int o0 = blockIdx.y * 64;
  const int s0 = blockIdx.x * 128;
  const int sx = tid & 15, oy = tid >> 4;
  float acc[4][8];
#pragma unroll
  for (int j = 0; j < 4; ++j)
#pragma unroll
    for (int l = 0; l < 8; ++l) acc[j][l] = 0.f;

  for (int i0 = 0; i0 < 256; i0 += 32) {
#pragma unroll
    for (int e4 = tid; e4 < 1024; e4 += 256) {
      int ii = e4 >> 5, ss4 = (e4 & 31) << 2;
      float4 v = *(const float4*)&x[(size_t)(b * NIN + i0 + ii) * NSEQ + s0 + ss4];
      *(float4*)&xs[ii][ss4] = v;
    }
#pragma unroll
    for (int e4 = tid; e4 < 512; e4 += 256) {
      int oj = e4 >> 3, ii4 = (e4 & 7) << 2;
      float4 v = *(const float4*)&Wuw[(o0 + oj) * NIN + i0 + ii4];
      wsh[ii4][oj] = v.x; wsh[ii4 + 1][oj] = v.y;
      wsh[ii4 + 2][oj] = v.z; wsh[ii4 + 3][oj] = v.w;
    }
    __syncthreads();
#pragma unroll 8
    for (int kk = 0; kk < 32; ++kk) {
      float4 a = *(const float4*)&wsh[kk][oy * 4];
      float4 b0 = *(const float4*)&xs[kk][sx * 4];
      float4 b1 = *(const float4*)&xs[kk][64 + sx * 4];
      float av[4] = {a.x, a.y, a.z, a.w};
      float bv[8] = {b0.x, b0.y, b0.z, b0.w, b1.x, b1.y, b1.z, b1.w};
#pragma unroll
      for (int j = 0; j < 4; ++j)
#pragma unroll
        for (int l = 0; l < 8; ++l) acc[j][l] = fmaf(av[j], bv[l], acc[j][l]);
    }
    __syncthreads();
  }
#pragma unroll
  for (int j = 0; j < 4; ++j) {
    int o = o0 + oy * 4 + j;
    if (o < NHID) {
      float bias = Wub[o] + Whb[o];
      size_t base = ((size_t)b * NHID + o) * NSEQ + s0;
      float4 v0 = make_float4(acc[j][0] + bias, acc[j][1] + bias,
                              acc[j][2] + bias, acc[j][3] + bias);
      float4 v1 = make_float4(acc[j][4] + bias, acc[j][5] + bias,
                              acc[j][6] + bias, acc[j][7] + bias);
      *(float4*)&dout[base + sx * 4] = v0;
      *(float4*)&dout[base + 64 + sx * 4] = v1;
    } else {
      float bias = Wub[o];
      size_t base = ((size_t)b * NFEAT + (o - NHID)) * NSEQ + s0;
      float4 v0 = make_float4(fmaxf(acc[j][0] + bias, 0.f), fmaxf(acc[j][1] + bias, 0.f),
                              fmaxf(acc[j][2] + bias, 0.f), fmaxf(acc[j][3] + bias, 0.f));
      float4 v1 = make_float4(fmaxf(acc[j][4] + bias, 0.f), fmaxf(acc[j][5] + bias, 0.f),
                              fmaxf(acc[j][6] + bias, 0.f), fmaxf(acc[j][7] + bias, 0.f));
      *(float4*)&ubuf[base + sx * 4] = v0;
      *(float4*)&ubuf[base + 64 + sx * 4] = v1;
    }
  }
}

// ---------------------------------------------------------------------------
// k2f: fft_u[b,f,k] = rfft(ubuf[b,f,:], n=4096)[k] via LDS FFT. 1 block/row.
// ---------------------------------------------------------------------------
__global__ __launch_bounds__(256) void k2f(
    const float* __restrict__ ubuf, const float2* __restrict__ tw,
    float* __restrict__ fftu) {
  __shared__ float XR[FFT_LDS], XI[FFT_LDS];
  __shared__ float2 TWS[2048];
  const int tid = threadIdx.x;
  const int b = blockIdx.x >> 6, f = blockIdx.x & 63;
  const float* src = ubuf + ((size_t)b * NFEAT + f) * NSEQ;
  for (int i = tid; i < NFFT; i += 256) { XR[FIDX(i)] = 0.f; XI[FIDX(i)] = 0.f; }
  for (int i = tid; i < 2048; i += 256) TWS[i] = tw[i];
  __syncthreads();
  for (int i = tid; i < NSEQ; i += 256) {
    int r = __brev((unsigned)i) >> 20;
    XR[FIDX(r)] = src[i];
  }
  __syncthreads();
  fft4096_core(XR, XI, TWS, false);
  float2* dst = (float2*)fftu + ((size_t)b * NFEAT + f) * KBINS;
  for (int k = tid; k < KBINS; k += 256)
    dst[k] = make_float2(XR[FIDX(k)], XI[FIDX(k)]);
}

// ---------------------------------------------------------------------------
// k3o: fused G+Z for one o-chunk (32 o's), all k.
//   G[o,f,k] = sum_mi Wh_w[o, f*64+mi] * fHd[mi,k]
//   Zc[b,olocal,k] = sum_f fft_u[b,f,k] * G[o,f,k]
// ---------------------------------------------------------------------------
__global__ __launch_bounds__(256) void k3o(
    const float* __restrict__ Whw, const float* __restrict__ fHd,
    const float* __restrict__ fftu, float* __restrict__ Zc, int ob0) {
  __shared__ float2 WhP[4096];
  __shared__ float2 fHc[64][65];
  __shared__ float red[4][64][33];
  const int tid = threadIdx.x;
  const int ol0 = blockIdx.x * 2;          // o_local base (0..30)
  const int o0 = ob0 + ol0;
  const int k0 = blockIdx.y * 64;

  for (int e = tid; e < 4096; e += 256)
    WhP[e] = make_float2(Whw[(size_t)o0 * 4096 + e],
                         Whw[(size_t)(o0 + 1) * 4096 + e]);
  for (int e = tid; e < 4096; e += 256) {
    int mi = e >> 6, kk = e & 63;
    int k = k0 + kk;
    float2 v = make_float2(0.f, 0.f);
    if (k < KBINS) v = ((const float2*)fHd)[(size_t)mi * KBINS + k];
    fHc[mi][kk] = v;
  }
  __syncthreads();

  const int tk = tid & 63, g = tid >> 6;
  const int k = k0 + tk;
  const bool kok = (k < KBINS);
  float zr[2][8], zi[2][8];
#pragma unroll
  for (int ol = 0; ol < 2; ++ol)
#pragma unroll
    for (int b = 0; b < 8; ++b) { zr[ol][b] = 0.f; zi[ol][b] = 0.f; }

  const float2* fu2 = (const float2*)fftu;
  for (int ff = 0; ff < 16; ++ff) {
    const int f = g * 16 + ff;
    float g0r = 0.f, g0i = 0.f, g1r = 0.f, g1i = 0.f;
#pragma unroll 16
    for (int mi = 0; mi < 64; ++mi) {
      float2 h = fHc[mi][tk];
      float2 w = WhP[f * 64 + mi];
      g0r = fmaf(w.x, h.x, g0r); g0i = fmaf(w.x, h.y, g0i);
      g1r = fmaf(w.y, h.x, g1r); g1i = fmaf(w.y, h.y, g1i);
    }
    if (kok) {
#pragma unroll
      for (int b = 0; b < 8; ++b) {
        float2 u = fu2[(size_t)(b * NFEAT + f) * KBINS + k];
        zr[0][b] = fmaf(u.x, g0r, fmaf(-u.y, g0i, zr[0][b]));
        zi[0][b] = fmaf(u.x, g0i, fmaf( u.y, g0r, zi[0][b]));
        zr[1][b] = fmaf(u.x, g1r, fmaf(-u.y, g1i, zr[1][b]));
        zi[1][b] = fmaf(u.x, g1i, fmaf( u.y, g1r, zi[1][b]));
      }
    }
  }
#pragma unroll
  for (int ol = 0; ol < 2; ++ol)
#pragma unroll
    for (int b = 0; b < 8; ++b) {
      red[g][tk][(ol * 8 + b) * 2 + 0] = zr[ol][b];
      red[g][tk][(ol * 8 + b) * 2 + 1] = zi[ol][b];
    }
  __syncthreads();
  if (g == 0 && kok) {
    float2* Z2 = (float2*)Zc;
#pragma unroll
    for (int ol = 0; ol < 2; ++ol)
#pragma unroll
      for (int b = 0; b < 8; ++b) {
        int i0 = (ol * 8 + b) * 2;
        float sr = red[0][tk][i0]     + red[1][tk][i0]
                 + red[2][tk][i0]     + red[3][tk][i0];
        float si = red[0][tk][i0 + 1] + red[1][tk][i0 + 1]
                 + red[2][tk][i0 + 1] + red[3][tk][i0 + 1];
        Z2[((size_t)b * OCH + ol0 + ol) * KBINS + k] = make_float2(sr, si);
      }
  }
}

// ---------------------------------------------------------------------------
// k4f: irfft via LDS FFT; dout[b,o,t] += XR[t]/4096. 1 block per (b,olocal).
// ---------------------------------------------------------------------------
__global__ __launch_bounds__(256) void k4f(
    const float* __restrict__ Zc, const float2* __restrict__ tw,
    float* __restrict__ dout, int ob0) {
  __shared__ float XR[FFT_LDS], XI[FFT_LDS];
  __shared__ float2 TWS[2048];
  const int tid = threadIdx.x;
  const int b = blockIdx.x >> 5, ol = blockIdx.x & 31;
  const int o = ob0 + ol;
  const float2* Z2 = (const float2*)Zc + ((size_t)b * OCH + ol) * KBINS;
  for (int i = tid; i < 2048; i += 256) TWS[i] = tw[i];
  for (int i = tid; i < NFFT; i += 256) {
    float2 v;
    if (i < KBINS) v = Z2[i];
    else { v = Z2[NFFT - i]; v.y = -v.y; }
    int r = __brev((unsigned)i) >> 20;
    XR[FIDX(r)] = v.x; XI[FIDX(r)] = v.y;
  }
  __syncthreads();
  fft4096_core(XR, XI, TWS, true);
  const float inv = 1.0f / (float)NFFT;
  float* drow = dout + ((size_t)b * NHID + o) * NSEQ;
  for (int t = tid; t < NSEQ; t += 256)
    drow[t] += XR[FIDX(t)] * inv;
}

// ---------------------------------------------------------------------------
extern "C" void kernel_launch(void* const* d_in, const int* in_sizes, int n_in,
                              void* d_out, int out_size, void* d_ws, size_t ws_size,
                              hipStream_t stream) {
  const float* x   = (const float*)d_in[0];
  const float* Wuw = (const float*)d_in[1];
  const float* Wub = (const float*)d_in[2];
  const float* Whw = (const float*)d_in[3];
  const float* Whb = (const float*)d_in[4];
  // d_in[5] (fft_H) intentionally UNUSED: recomputed on-device in fp64.
  float* out = (float*)d_out;
  float* ws  = (float*)d_ws;

  float* fftu = ws + FFTU_OFF;
  float* uz   = ws + UZ_OFF;       // f64 scratch -> ubuf -> Z o-chunks
  float* fHd  = ws + FHD_OFF;
  float2* tw  = (float2*)(ws + TW_OFF);
  float* Hbuf = ws + HBUF_OFF;
  double* D   = (double*)uz;

  k0_tw<<<8, 256, 0, stream>>>(tw);

  // --- kA chain: expm + power tables, ~54 tiny L2-resident launches ---
  kblk<<<17, 256, 0, stream>>>(D + DMM);
  kinitTE<<<17, 256, 0, stream>>>(D + DTT0, D + DEE0);
  {
    double* t0 = D + DTT0;
    double* t1 = D + DTT1;
    for (int k = 1; k <= 29; ++k) {
      kmm65<<<17, 256, 0, stream>>>(t0, D + DMM, t1, D + DEE0, (double)k);
      double* tmp = t0; t0 = t1; t1 = tmp;
    }
  }
  kmm65<<<17, 256, 0, stream>>>(D + DEE0, D + DEE0, D + DEE1, (double*)nullptr, 1.0);
  kmm65<<<17, 256, 0, stream>>>(D + DEE1, D + DEE1, D + DEE0, (double*)nullptr, 1.0);
  kext<<<17, 256, 0, stream>>>(D + DEE0, D);
  // pw[m] = Ad^(2^m), m=1..5
  for (int m = 1; m <= 5; ++m)
    kmm64<<<16, 256, 0, stream>>>(D + DPW + (m - 1) * 4096,
                                  D + DPW + (m - 1) * 4096,
                                  D + DPW + m * 4096);
  // Mk[1] = Ad^64 = pw5 @ pw5
  kmm64<<<16, 256, 0, stream>>>(D + DPW + 5 * 4096, D + DPW + 5 * 4096,
                                D + DMK2 + 4096);
  // W log-doubling: W[b0+t] = pw[m] @ W[t]
  for (int m = 0; m <= 5; ++m)
    kwlev<<<1, 256, 0, stream>>>(D + DPW + m * 4096, D + DWV, 1 << m);
  // Mk log-doubling
  for (int m = 1; m <= 4; ++m) {
    int b0 = 1 << m;
    kmm64<<<16, 256, 0, stream>>>(D + DMK2 + (size_t)(b0 / 2) * 4096,
                                  D + DMK2 + (size_t)(b0 / 2) * 4096,
                                  D + DMK2 + (size_t)b0 * 4096);
    int cnt = b0 - 1;
    kmk<<<dim3(16, cnt), 256, 0, stream>>>(D + DMK2 + (size_t)b0 * 4096,
                                           D + DMK2 + 4096,
                                           D + DMK2 + (size_t)(b0 + 1) * 4096);
  }

  kB_cols<<<32, 256, 0, stream>>>(D, Hbuf);
  kC_fft<<<NMEM, 256, 0, stream>>>(Hbuf, tw, fHd);
  k1t<<<dim3(NSEQ / 128, NOUTCH / 64, NB), 256, 0, stream>>>(x, Wuw, Wub, Whb, out, uz);
  k2f<<<NB * NFEAT, 256, 0, stream>>>(uz, tw, fftu);
  for (int oc = 0; oc < NOCH; ++oc) {
    int ob0 = oc * OCH;
    k3o<<<dim3(OCH / 2, (KBINS + 63) / 64), 256, 0, stream>>>(Whw, fHd, fftu, uz, ob0);
    k4f<<<NB * OCH, 256, 0, stream>>>(uz, tw, out, ob0);
  }
}

// Round 12
// 1086.019 us; speedup vs baseline: 7.1991x; 1.1303x over previous
//
#include <hip/hip_runtime.h>
#include <hip/hip_bf16.h>
#include <math.h>

// Problem constants
#define NB 8
#define NIN 256
#define NHID 256
#define NMEM 64
#define NSEQ 2048
#define NFEAT 64
#define NOUTCH 320        // NFEAT + NHID
#define NFFT 4096
#define KBINS 2049        // NSEQ + 1
#define OCH 32            // o-chunk size
#define NOCH 8            // 256 / 32

// ws layout (float offsets) — TOTAL 14.18 MB
#define FFTU_OFF 0
#define FFTU_SZ (NB * NFEAT * KBINS * 2)               // 2,098,176 (8.4 MB)
#define UZ_OFF (FFTU_OFF + FFTU_SZ)                    // overlay: f64 scratch -> ubuf -> Z o-chunks
#define UZ_SZ (NB * OCH * KBINS * 2)                   // 1,049,088 (4.2 MB)
#define FHD_OFF (UZ_OFF + UZ_SZ)
#define FHD_SZ (NMEM * KBINS * 2)                      // 262,272 (1.05 MB)
#define TW_OFF (FHD_OFF + FHD_SZ)
#define TW_SZ (2048 * 2)                               // 16 KB
#define HBUF_OFF (TW_OFF + TW_SZ)
#define HBUF_SZ (NMEM * NSEQ)                          // 131,072 (0.52 MB)

// f64 scratch layout (doubles, based at UZ_OFF; dead before ubuf is written)
#define DMM   0                      // 65x65 scaled blk
#define DTT0  4225                   // Taylor T ping
#define DTT1  8450                   // Taylor T pong
#define DEE0  12675                  // E ping
#define DEE1  16900                  // E pong
#define DPW   21125                  // pw[0..5] = Ad^(2^m), 6*4096
#define DWV   (DPW + 6 * 4096)       // W[r][j] = (Ad^r Bd)[j], 64x64
#define DMK2  (DWV + 4096)           // Mk[k] = (Ad^64)^k, 32*4096

// padded LDS index for FFT arrays (breaks power-of-2 stride bank conflicts)
#define FIDX(i) ((i) + ((i) >> 5) + ((i) >> 10))
#define FFT_LDS 4240

// ---------------------------------------------------------------------------
// shared 4096-pt radix-2 DIT core (data already bit-reversed into XR/XI)
// ---------------------------------------------------------------------------
__device__ __forceinline__ void fft4096_core(float* XR, float* XI,
                                             const float2* TWS, bool inverse) {
#pragma unroll 1
  for (int s = 1; s <= 12; ++s) {
    int half = 1 << (s - 1);
    int shift = 12 - s;
#pragma unroll
    for (int q = 0; q < 8; ++q) {
      int bf = threadIdx.x + q * 256;
      int j = bf & (half - 1);
      int base = ((bf >> (s - 1)) << s) + j;
      float2 w = TWS[j << shift];
      float wr = w.x, wi = inverse ? -w.y : w.y;
      int i0 = FIDX(base), i1 = FIDX(base + half);
      float ar = XR[i0], ai = XI[i0];
      float br = XR[i1], bi = XI[i1];
      float tr = wr * br - wi * bi, ti = wr * bi + wi * br;
      XR[i0] = ar + tr; XI[i0] = ai + ti;
      XR[i1] = ar - tr; XI[i1] = ai - ti;
    }
    __syncthreads();
  }
}

// ---------------------------------------------------------------------------
// k0: tw[m] = exp(-2*pi*i*m/4096), m in [0,2048), double precision.
// ---------------------------------------------------------------------------
__global__ void k0_tw(float2* __restrict__ tw) {
  int m = blockIdx.x * 256 + threadIdx.x;
  if (m < 2048) {
    double ang = -2.0 * 3.14159265358979323846 * (double)m / 4096.0;
    tw[m] = make_float2((float)cos(ang), (float)sin(ang));
  }
}

// ---------------------------------------------------------------------------
// kA chain: expm + power tables as ~54 tiny L2-resident fp64 launches.
// norm1(blk) == 2.0 exactly => s=2, scale=0.25 hardcoded.
// ---------------------------------------------------------------------------
__global__ __launch_bounds__(256) void kblk(double* __restrict__ M) {
  int e = blockIdx.x * 256 + threadIdx.x;
  if (e < 4225) {
    int i = e / 65, j = e % 65;
    double val = 0.0;
    if (i < 64) {
      double R = (2.0 * i + 1.0) / 2048.0;
      if (j < 64) val = R * ((i < j) ? -1.0 : (((i - j) & 1) ? 1.0 : -1.0));
      else        val = R * ((i & 1) ? -1.0 : 1.0);   // Bc = R*(-1)^i
    }
    M[e] = 0.25 * val;
  }
}
__global__ __launch_bounds__(256) void kinitTE(double* __restrict__ T,
                                               double* __restrict__ E) {
  int e = blockIdx.x * 256 + threadIdx.x;
  if (e < 4225) {
    double id = ((e / 65) == (e % 65)) ? 1.0 : 0.0;
    T[e] = id; E[e] = id;
  }
}
__global__ __launch_bounds__(256) void kmm65(const double* __restrict__ A,
                                             const double* __restrict__ B,
                                             double* __restrict__ C,
                                             double* __restrict__ E, double kd) {
  int e = blockIdx.x * 256 + threadIdx.x;
  if (e >= 4225) return;
  int i = e / 65, j = e % 65;
  const double* ar = A + i * 65;
  double dot = 0.0;
  for (int l = 0; l < 65; ++l) dot += ar[l] * B[l * 65 + j];
  dot /= kd;
  C[e] = dot;
  if (E) E[e] += dot;
}
__global__ __launch_bounds__(256) void kext(const double* __restrict__ E,
                                            double* __restrict__ D) {
  int e = blockIdx.x * 256 + threadIdx.x;
  if (e < 4096) {
    int i = e >> 6, j = e & 63;
    D[DPW + e] = (double)(float)E[i * 65 + j];
    D[DMK2 + e] = (i == j) ? 1.0 : 0.0;
  } else if (e < 4160) {
    int j = e - 4096;
    D[DWV + j] = (double)(float)E[j * 65 + 64];
  }
}
__global__ __launch_bounds__(256) void kmm64(const double* __restrict__ A,
                                             const double* __restrict__ B,
                                             double* __restrict__ C) {
  int e = blockIdx.x * 256 + threadIdx.x;
  int i = e >> 6, j = e & 63;
  double dot = 0.0;
  for (int l = 0; l < 64; ++l) dot += A[i * 64 + l] * B[l * 64 + j];
  C[e] = dot;
}
__global__ __launch_bounds__(256) void kwlev(const double* __restrict__ P,
                                             double* __restrict__ W, int b0) {
  int tot = 64 * b0;
  for (int e = threadIdx.x; e < tot; e += 256) {
    int t = e >> 6, i = e & 63;
    double dot = 0.0;
    for (int l = 0; l < 64; ++l) dot += P[i * 64 + l] * W[t * 64 + l];
    W[(size_t)(b0 + t) * 64 + i] = dot;
  }
}
__global__ __launch_bounds__(256) void kmk(const double* __restrict__ Q,
                                           const double* __restrict__ Src,
                                           double* __restrict__ Out) {
  int t = blockIdx.y;
  int e = blockIdx.x * 256 + threadIdx.x;
  int i = e >> 6, j = e & 63;
  const double* B = Src + (size_t)t * 4096;
  double dot = 0.0;
  for (int l = 0; l < 64; ++l) dot += Q[i * 64 + l] * B[l * 64 + j];
  Out[(size_t)t * 4096 + e] = dot;
}

// ---------------------------------------------------------------------------
// kB: parallel impulse response. Block k (of 32): H[i, 64k+r] = Mk[k] @ W[r].
// ---------------------------------------------------------------------------
__global__ __launch_bounds__(256) void kB_cols(const double* __restrict__ D,
                                               float* __restrict__ H) {
  const double* W = D + DWV;
  const double* Mrow = D + DMK2 + (size_t)blockIdx.x * 4096;
  __shared__ double Ms[4096];
  const int tid = threadIdx.x;
  for (int e = tid; e < 4096; e += 256) Ms[e] = Mrow[e];
  __syncthreads();
  const int c0 = blockIdx.x * 64;
  for (int e = tid; e < 4096; e += 256) {
    int i = e >> 6, r = e & 63;
    double dot = 0.0;
#pragma unroll 16
    for (int j = 0; j < 64; ++j) dot += Ms[i * 64 + j] * W[r * 64 + j];
    H[(size_t)i * NSEQ + c0 + r] = (float)dot;
  }
}

// ---------------------------------------------------------------------------
// kC: fHd[mi,k] = rfft(H[mi,:], n=4096)[k] via LDS FFT. 1 block/row.
// ---------------------------------------------------------------------------
__global__ __launch_bounds__(256) void kC_fft(const float* __restrict__ H,
                                              const float2* __restrict__ tw,
                                              float* __restrict__ fHd) {
  __shared__ float XR[FFT_LDS], XI[FFT_LDS];
  __shared__ float2 TWS[2048];
  const int tid = threadIdx.x;
  const int mi = blockIdx.x;
  const float* src = H + (size_t)mi * NSEQ;
  for (int i = tid; i < NFFT; i += 256) { XR[FIDX(i)] = 0.f; XI[FIDX(i)] = 0.f; }
  for (int i = tid; i < 2048; i += 256) TWS[i] = tw[i];
  __syncthreads();
  for (int i = tid; i < NSEQ; i += 256) {
    int r = __brev((unsigned)i) >> 20;
    XR[FIDX(r)] = src[i];
  }
  __syncthreads();
  fft4096_core(XR, XI, TWS, false);
  float2* dst = (float2*)fHd + (size_t)mi * KBINS;
  for (int k = tid; k < KBINS; k += 256)
    dst[k] = make_float2(XR[FIDX(k)], XI[FIDX(k)]);
}

// ---------------------------------------------------------------------------
// k1t: tiled GEMM out[b,o,s] = bias + sum_i Wu_w[o,i]*x[b,i,s]
//   o<256 -> dout = acc + Wu_b + Wh_b ; o>=256 -> ubuf = relu(acc + Wu_b)
// ---------------------------------------------------------------------------
__global__ __launch_bounds__(256) void k1t(
    const float* __restrict__ x, const float* __restrict__ Wuw,
    const float* __restrict__ Wub, const float* __restrict__ Whb,
    float* __restrict__ dout, float* __restrict__ ubuf) {
  __shared__ float xs[32][128];
  __shared__ float wsh[32][68];
  const int tid = threadIdx.x;
  const int b = blockIdx.z;
  const int o0 = blockIdx.y * 64;
  const int s0 = blockIdx.x * 128;
  const int sx = tid & 15, oy = tid >> 4;
  float acc[4][8];
#pragma unroll
  for (int j = 0; j < 4; ++j)
#pragma unroll
    for (int l = 0; l < 8; ++l) acc[j][l] = 0.f;

  for (int i0 = 0; i0 < 256; i0 += 32) {
#pragma unroll
    for (int e4 = tid; e4 < 1024; e4 += 256) {
      int ii = e4 >> 5, ss4 = (e4 & 31) << 2;
      float4 v = *(const float4*)&x[(size_t)(b * NIN + i0 + ii) * NSEQ + s0 + ss4];
      *(float4*)&xs[ii][ss4] = v;
    }
#pragma unroll
    for (int e4 = tid; e4 < 512; e4 += 256) {
      int oj = e4 >> 3, ii4 = (e4 & 7) << 2;
      float4 v = *(const float4*)&Wuw[(o0 + oj) * NIN + i0 + ii4];
      wsh[ii4][oj] = v.x; wsh[ii4 + 1][oj] = v.y;
      wsh[ii4 + 2][oj] = v.z; wsh[ii4 + 3][oj] = v.w;
    }
    __syncthreads();
#pragma unroll 8
    for (int kk = 0; kk < 32; ++kk) {
      float4 a = *(const float4*)&wsh[kk][oy * 4];
      float4 b0 = *(const float4*)&xs[kk][sx * 4];
      float4 b1 = *(const float4*)&xs[kk][64 + sx * 4];
      float av[4] = {a.x, a.y, a.z, a.w};
      float bv[8] = {b0.x, b0.y, b0.z, b0.w, b1.x, b1.y, b1.z, b1.w};
#pragma unroll
      for (int j = 0; j < 4; ++j)
#pragma unroll
        for (int l = 0; l < 8; ++l) acc[j][l] = fmaf(av[j], bv[l], acc[j][l]);
    }
    __syncthreads();
  }
#pragma unroll
  for (int j = 0; j < 4; ++j) {
    int o = o0 + oy * 4 + j;
    if (o < NHID) {
      float bias = Wub[o] + Whb[o];
      size_t base = ((size_t)b * NHID + o) * NSEQ + s0;
      float4 v0 = make_float4(acc[j][0] + bias, acc[j][1] + bias,
                              acc[j][2] + bias, acc[j][3] + bias);
      float4 v1 = make_float4(acc[j][4] + bias, acc[j][5] + bias,
                              acc[j][6] + bias, acc[j][7] + bias);
      *(float4*)&dout[base + sx * 4] = v0;
      *(float4*)&dout[base + 64 + sx * 4] = v1;
    } else {
      float bias = Wub[o];
      size_t base = ((size_t)b * NFEAT + (o - NHID)) * NSEQ + s0;
      float4 v0 = make_float4(fmaxf(acc[j][0] + bias, 0.f), fmaxf(acc[j][1] + bias, 0.f),
                              fmaxf(acc[j][2] + bias, 0.f), fmaxf(acc[j][3] + bias, 0.f));
      float4 v1 = make_float4(fmaxf(acc[j][4] + bias, 0.f), fmaxf(acc[j][5] + bias, 0.f),
                              fmaxf(acc[j][6] + bias, 0.f), fmaxf(acc[j][7] + bias, 0.f));
      *(float4*)&ubuf[base + sx * 4] = v0;
      *(float4*)&ubuf[base + 64 + sx * 4] = v1;
    }
  }
}

// ---------------------------------------------------------------------------
// k2f: fft_u[b,f,k] = rfft(ubuf[b,f,:], n=4096)[k] via LDS FFT. 1 block/row.
// ---------------------------------------------------------------------------
__global__ __launch_bounds__(256) void k2f(
    const float* __restrict__ ubuf, const float2* __restrict__ tw,
    float* __restrict__ fftu) {
  __shared__ float XR[FFT_LDS], XI[FFT_LDS];
  __shared__ float2 TWS[2048];
  const int tid = threadIdx.x;
  const int b = blockIdx.x >> 6, f = blockIdx.x & 63;
  const float* src = ubuf + ((size_t)b * NFEAT + f) * NSEQ;
  for (int i = tid; i < NFFT; i += 256) { XR[FIDX(i)] = 0.f; XI[FIDX(i)] = 0.f; }
  for (int i = tid; i < 2048; i += 256) TWS[i] = tw[i];
  __syncthreads();
  for (int i = tid; i < NSEQ; i += 256) {
    int r = __brev((unsigned)i) >> 20;
    XR[FIDX(r)] = src[i];
  }
  __syncthreads();
  fft4096_core(XR, XI, TWS, false);
  float2* dst = (float2*)fftu + ((size_t)b * NFEAT + f) * KBINS;
  for (int k = tid; k < KBINS; k += 256)
    dst[k] = make_float2(XR[FIDX(k)], XI[FIDX(k)]);
}

// ---------------------------------------------------------------------------
// k3o: fused G+Z for one o-chunk (32 o's), all k.
//   G[o,f,k] = sum_mi Wh_w[o, f*64+mi] * fHd[mi,k]
//   Zc[b,olocal,k] = sum_f fft_u[b,f,k] * G[o,f,k]
// Round-11 post-mortem: 99.8 KB LDS => 1 block/CU => VALUBusy 18.7%.
// Fix: `red` (used only AFTER the main loop) overlays WhP/fHc (used only
// DURING it) => 66 KB => 2 blocks/CU.
// ---------------------------------------------------------------------------
#define K3_SMEM 16512   // floats: WhP 8192 + fHc 8320 (64x65 float2)
__global__ __launch_bounds__(256) void k3o(
    const float* __restrict__ Whw, const float* __restrict__ fHd,
    const float* __restrict__ fftu, float* __restrict__ Zc, int ob0) {
  __shared__ float smem[K3_SMEM];
  float2* WhP = (float2*)smem;                    // [4096]
  float2 (*fHc)[65] = (float2(*)[65])(smem + 8192);  // [64][65]
  float (*red)[64][33] = (float(*)[64][33])smem;  // overlay, post-loop only
  const int tid = threadIdx.x;
  const int ol0 = blockIdx.x * 2;          // o_local base (0..30)
  const int o0 = ob0 + ol0;
  const int k0 = blockIdx.y * 64;

  for (int e = tid; e < 4096; e += 256)
    WhP[e] = make_float2(Whw[(size_t)o0 * 4096 + e],
                         Whw[(size_t)(o0 + 1) * 4096 + e]);
  for (int e = tid; e < 4096; e += 256) {
    int mi = e >> 6, kk = e & 63;
    int k = k0 + kk;
    float2 v = make_float2(0.f, 0.f);
    if (k < KBINS) v = ((const float2*)fHd)[(size_t)mi * KBINS + k];
    fHc[mi][kk] = v;
  }
  __syncthreads();

  const int tk = tid & 63, g = tid >> 6;
  const int k = k0 + tk;
  const bool kok = (k < KBINS);
  float zr[2][8], zi[2][8];
#pragma unroll
  for (int ol = 0; ol < 2; ++ol)
#pragma unroll
    for (int b = 0; b < 8; ++b) { zr[ol][b] = 0.f; zi[ol][b] = 0.f; }

  const float2* fu2 = (const float2*)fftu;
  for (int ff = 0; ff < 16; ++ff) {
    const int f = g * 16 + ff;
    float g0r = 0.f, g0i = 0.f, g1r = 0.f, g1i = 0.f;
#pragma unroll 16
    for (int mi = 0; mi < 64; ++mi) {
      float2 h = fHc[mi][tk];
      float2 w = WhP[f * 64 + mi];
      g0r = fmaf(w.x, h.x, g0r); g0i = fmaf(w.x, h.y, g0i);
      g1r = fmaf(w.y, h.x, g1r); g1i = fmaf(w.y, h.y, g1i);
    }
    if (kok) {
#pragma unroll
      for (int b = 0; b < 8; ++b) {
        float2 u = fu2[(size_t)(b * NFEAT + f) * KBINS + k];
        zr[0][b] = fmaf(u.x, g0r, fmaf(-u.y, g0i, zr[0][b]));
        zi[0][b] = fmaf(u.x, g0i, fmaf( u.y, g0r, zi[0][b]));
        zr[1][b] = fmaf(u.x, g1r, fmaf(-u.y, g1i, zr[1][b]));
        zi[1][b] = fmaf(u.x, g1i, fmaf( u.y, g1r, zi[1][b]));
      }
    }
  }
  __syncthreads();   // WhP/fHc dead; red overlays them
#pragma unroll
  for (int ol = 0; ol < 2; ++ol)
#pragma unroll
    for (int b = 0; b < 8; ++b) {
      red[g][tk][(ol * 8 + b) * 2 + 0] = zr[ol][b];
      red[g][tk][(ol * 8 + b) * 2 + 1] = zi[ol][b];
    }
  __syncthreads();
  if (g == 0 && kok) {
    float2* Z2 = (float2*)Zc;
#pragma unroll
    for (int ol = 0; ol < 2; ++ol)
#pragma unroll
      for (int b = 0; b < 8; ++b) {
        int i0 = (ol * 8 + b) * 2;
        float sr = red[0][tk][i0]     + red[1][tk][i0]
                 + red[2][tk][i0]     + red[3][tk][i0];
        float si = red[0][tk][i0 + 1] + red[1][tk][i0 + 1]
                 + red[2][tk][i0 + 1] + red[3][tk][i0 + 1];
        Z2[((size_t)b * OCH + ol0 + ol) * KBINS + k] = make_float2(sr, si);
      }
  }
}

// ---------------------------------------------------------------------------
// k4f: irfft via LDS FFT; dout[b,o,t] += XR[t]/4096. 1 block per (b,olocal).
// ---------------------------------------------------------------------------
__global__ __launch_bounds__(256) void k4f(
    const float* __restrict__ Zc, const float2* __restrict__ tw,
    float* __restrict__ dout, int ob0) {
  __shared__ float XR[FFT_LDS], XI[FFT_LDS];
  __shared__ float2 TWS[2048];
  const int tid = threadIdx.x;
  const int b = blockIdx.x >> 5, ol = blockIdx.x & 31;
  const int o = ob0 + ol;
  const float2* Z2 = (const float2*)Zc + ((size_t)b * OCH + ol) * KBINS;
  for (int i = tid; i < 2048; i += 256) TWS[i] = tw[i];
  for (int i = tid; i < NFFT; i += 256) {
    float2 v;
    if (i < KBINS) v = Z2[i];
    else { v = Z2[NFFT - i]; v.y = -v.y; }
    int r = __brev((unsigned)i) >> 20;
    XR[FIDX(r)] = v.x; XI[FIDX(r)] = v.y;
  }
  __syncthreads();
  fft4096_core(XR, XI, TWS, true);
  const float inv = 1.0f / (float)NFFT;
  float* drow = dout + ((size_t)b * NHID + o) * NSEQ;
  for (int t = tid; t < NSEQ; t += 256)
    drow[t] += XR[FIDX(t)] * inv;
}

// ---------------------------------------------------------------------------
extern "C" void kernel_launch(void* const* d_in, const int* in_sizes, int n_in,
                              void* d_out, int out_size, void* d_ws, size_t ws_size,
                              hipStream_t stream) {
  const float* x   = (const float*)d_in[0];
  const float* Wuw = (const float*)d_in[1];
  const float* Wub = (const float*)d_in[2];
  const float* Whw = (const float*)d_in[3];
  const float* Whb = (const float*)d_in[4];
  // d_in[5] (fft_H) intentionally UNUSED: recomputed on-device in fp64.
  float* out = (float*)d_out;
  float* ws  = (float*)d_ws;

  float* fftu = ws + FFTU_OFF;
  float* uz   = ws + UZ_OFF;       // f64 scratch -> ubuf -> Z o-chunks
  float* fHd  = ws + FHD_OFF;
  float2* tw  = (float2*)(ws + TW_OFF);
  float* Hbuf = ws + HBUF_OFF;
  double* D   = (double*)uz;

  k0_tw<<<8, 256, 0, stream>>>(tw);

  // --- kA chain: expm + power tables ---
  kblk<<<17, 256, 0, stream>>>(D + DMM);
  kinitTE<<<17, 256, 0, stream>>>(D + DTT0, D + DEE0);
  {
    double* t0 = D + DTT0;
    double* t1 = D + DTT1;
    for (int k = 1; k <= 29; ++k) {
      kmm65<<<17, 256, 0, stream>>>(t0, D + DMM, t1, D + DEE0, (double)k);
      double* tmp = t0; t0 = t1; t1 = tmp;
    }
  }
  kmm65<<<17, 256, 0, stream>>>(D + DEE0, D + DEE0, D + DEE1, (double*)nullptr, 1.0);
  kmm65<<<17, 256, 0, stream>>>(D + DEE1, D + DEE1, D + DEE0, (double*)nullptr, 1.0);
  kext<<<17, 256, 0, stream>>>(D + DEE0, D);
  for (int m = 1; m <= 5; ++m)
    kmm64<<<16, 256, 0, stream>>>(D + DPW + (m - 1) * 4096,
                                  D + DPW + (m - 1) * 4096,
                                  D + DPW + m * 4096);
  kmm64<<<16, 256, 0, stream>>>(D + DPW + 5 * 4096, D + DPW + 5 * 4096,
                                D + DMK2 + 4096);
  for (int m = 0; m <= 5; ++m)
    kwlev<<<1, 256, 0, stream>>>(D + DPW + m * 4096, D + DWV, 1 << m);
  for (int m = 1; m <= 4; ++m) {
    int b0 = 1 << m;
    kmm64<<<16, 256, 0, stream>>>(D + DMK2 + (size_t)(b0 / 2) * 4096,
                                  D + DMK2 + (size_t)(b0 / 2) * 4096,
                                  D + DMK2 + (size_t)b0 * 4096);
    int cnt = b0 - 1;
    kmk<<<dim3(16, cnt), 256, 0, stream>>>(D + DMK2 + (size_t)b0 * 4096,
                                           D + DMK2 + 4096,
                                           D + DMK2 + (size_t)(b0 + 1) * 4096);
  }

  kB_cols<<<32, 256, 0, stream>>>(D, Hbuf);
  kC_fft<<<NMEM, 256, 0, stream>>>(Hbuf, tw, fHd);
  k1t<<<dim3(NSEQ / 128, NOUTCH / 64, NB), 256, 0, stream>>>(x, Wuw, Wub, Whb, out, uz);
  k2f<<<NB * NFEAT, 256, 0, stream>>>(uz, tw, fftu);
  for (int oc = 0; oc < NOCH; ++oc) {
    int ob0 = oc * OCH;
    k3o<<<dim3(OCH / 2, (KBINS + 63) / 64), 256, 0, stream>>>(Whw, fHd, fftu, uz, ob0);
    k4f<<<NB * OCH, 256, 0, stream>>>(uz, tw, out, ob0);
  }
}

// Round 13
// 1003.983 us; speedup vs baseline: 7.7873x; 1.0817x over previous
//
#include <hip/hip_runtime.h>
#include <hip/hip_bf16.h>
#include <math.h>

// Problem constants
#define NB 8
#define NIN 256
#define NHID 256
#define NMEM 64
#define NSEQ 2048
#define NFEAT 64
#define NOUTCH 320        // NFEAT + NHID
#define NFFT 4096
#define KBINS 2049        // NSEQ + 1
#define OCH 32            // o-chunk size
#define NOCH 8            // 256 / 32

// ws layout (float offsets) — TOTAL 14.18 MB
#define FFTU_OFF 0
#define FFTU_SZ (NB * NFEAT * KBINS * 2)               // 2,098,176 (8.4 MB)
#define UZ_OFF (FFTU_OFF + FFTU_SZ)                    // overlay: f64 scratch -> ubuf -> Z o-chunks
#define UZ_SZ (NB * OCH * KBINS * 2)                   // 1,049,088 (4.2 MB)
#define FHD_OFF (UZ_OFF + UZ_SZ)
#define FHD_SZ (NMEM * KBINS * 2)                      // 262,272 (1.05 MB)
#define TW_OFF (FHD_OFF + FHD_SZ)
#define TW_SZ (2048 * 2)                               // 16 KB
#define HBUF_OFF (TW_OFF + TW_SZ)
#define HBUF_SZ (NMEM * NSEQ)                          // 131,072 (0.52 MB)

// f64 scratch layout (doubles, based at UZ_OFF; dead before ubuf is written)
#define DMM   0                      // 65x65 scaled blk
#define DTT0  4225                   // Taylor T ping
#define DTT1  8450                   // Taylor T pong
#define DEE0  12675                  // E ping
#define DEE1  16900                  // E pong
#define DPW   21125                  // pw[0..5] = Ad^(2^m), 6*4096
#define DWV   (DPW + 6 * 4096)       // W[r][j] = (Ad^r Bd)[j], 64x64
#define DMK2  (DWV + 4096)           // Mk[k] = (Ad^64)^k, 32*4096

// padded LDS index for FFT arrays (breaks power-of-2 stride bank conflicts)
#define FIDX(i) ((i) + ((i) >> 5) + ((i) >> 10))
#define FFT_LDS 4240

// ---------------------------------------------------------------------------
// shared 4096-pt radix-2 DIT core (data already bit-reversed into XR/XI)
// ---------------------------------------------------------------------------
__device__ __forceinline__ void fft4096_core(float* XR, float* XI,
                                             const float2* TWS, bool inverse) {
#pragma unroll 1
  for (int s = 1; s <= 12; ++s) {
    int half = 1 << (s - 1);
    int shift = 12 - s;
#pragma unroll
    for (int q = 0; q < 8; ++q) {
      int bf = threadIdx.x + q * 256;
      int j = bf & (half - 1);
      int base = ((bf >> (s - 1)) << s) + j;
      float2 w = TWS[j << shift];
      float wr = w.x, wi = inverse ? -w.y : w.y;
      int i0 = FIDX(base), i1 = FIDX(base + half);
      float ar = XR[i0], ai = XI[i0];
      float br = XR[i1], bi = XI[i1];
      float tr = wr * br - wi * bi, ti = wr * bi + wi * br;
      XR[i0] = ar + tr; XI[i0] = ai + ti;
      XR[i1] = ar - tr; XI[i1] = ai - ti;
    }
    __syncthreads();
  }
}

// ---------------------------------------------------------------------------
// k0: tw[m] = exp(-2*pi*i*m/4096), m in [0,2048), double precision.
// ---------------------------------------------------------------------------
__global__ void k0_tw(float2* __restrict__ tw) {
  int m = blockIdx.x * 256 + threadIdx.x;
  if (m < 2048) {
    double ang = -2.0 * 3.14159265358979323846 * (double)m / 4096.0;
    tw[m] = make_float2((float)cos(ang), (float)sin(ang));
  }
}

// ---------------------------------------------------------------------------
// kA chain: expm + power tables as tiny L2-resident fp64 launches.
// norm1(blk) == 2.0 exactly => s=2, scale=0.25 hardcoded.
// Taylor cut 29->16 terms: term 17 ~ 0.5^17/17! ~ 2e-19 rel — below fp64 eps,
// invisible after the f32 rounding of Ad/Bd.
// ---------------------------------------------------------------------------
__global__ __launch_bounds__(256) void kblk(double* __restrict__ M) {
  int e = blockIdx.x * 256 + threadIdx.x;
  if (e < 4225) {
    int i = e / 65, j = e % 65;
    double val = 0.0;
    if (i < 64) {
      double R = (2.0 * i + 1.0) / 2048.0;
      if (j < 64) val = R * ((i < j) ? -1.0 : (((i - j) & 1) ? 1.0 : -1.0));
      else        val = R * ((i & 1) ? -1.0 : 1.0);   // Bc = R*(-1)^i
    }
    M[e] = 0.25 * val;
  }
}
__global__ __launch_bounds__(256) void kinitTE(double* __restrict__ T,
                                               double* __restrict__ E) {
  int e = blockIdx.x * 256 + threadIdx.x;
  if (e < 4225) {
    double id = ((e / 65) == (e % 65)) ? 1.0 : 0.0;
    T[e] = id; E[e] = id;
  }
}
__global__ __launch_bounds__(256) void kmm65(const double* __restrict__ A,
                                             const double* __restrict__ B,
                                             double* __restrict__ C,
                                             double* __restrict__ E, double kd) {
  int e = blockIdx.x * 256 + threadIdx.x;
  if (e >= 4225) return;
  int i = e / 65, j = e % 65;
  const double* ar = A + i * 65;
  double dot = 0.0;
  for (int l = 0; l < 65; ++l) dot += ar[l] * B[l * 65 + j];
  dot /= kd;
  C[e] = dot;
  if (E) E[e] += dot;
}
__global__ __launch_bounds__(256) void kext(const double* __restrict__ E,
                                            double* __restrict__ D) {
  int e = blockIdx.x * 256 + threadIdx.x;
  if (e < 4096) {
    int i = e >> 6, j = e & 63;
    D[DPW + e] = (double)(float)E[i * 65 + j];
    D[DMK2 + e] = (i == j) ? 1.0 : 0.0;
  } else if (e < 4160) {
    int j = e - 4096;
    D[DWV + j] = (double)(float)E[j * 65 + 64];
  }
}
__global__ __launch_bounds__(256) void kmm64(const double* __restrict__ A,
                                             const double* __restrict__ B,
                                             double* __restrict__ C) {
  int e = blockIdx.x * 256 + threadIdx.x;
  int i = e >> 6, j = e & 63;
  double dot = 0.0;
  for (int l = 0; l < 64; ++l) dot += A[i * 64 + l] * B[l * 64 + j];
  C[e] = dot;
}
__global__ __launch_bounds__(256) void kwlev(const double* __restrict__ P,
                                             double* __restrict__ W, int b0) {
  int tot = 64 * b0;
  for (int e = threadIdx.x; e < tot; e += 256) {
    int t = e >> 6, i = e & 63;
    double dot = 0.0;
    for (int l = 0; l < 64; ++l) dot += P[i * 64 + l] * W[t * 64 + l];
    W[(size_t)(b0 + t) * 64 + i] = dot;
  }
}
__global__ __launch_bounds__(256) void kmk(const double* __restrict__ Q,
                                           const double* __restrict__ Src,
                                           double* __restrict__ Out) {
  int t = blockIdx.y;
  int e = blockIdx.x * 256 + threadIdx.x;
  int i = e >> 6, j = e & 63;
  const double* B = Src + (size_t)t * 4096;
  double dot = 0.0;
  for (int l = 0; l < 64; ++l) dot += Q[i * 64 + l] * B[l * 64 + j];
  Out[(size_t)t * 4096 + e] = dot;
}

// ---------------------------------------------------------------------------
// kB: parallel impulse response. Block k (of 32): H[i, 64k+r] = Mk[k] @ W[r].
// ---------------------------------------------------------------------------
__global__ __launch_bounds__(256) void kB_cols(const double* __restrict__ D,
                                               float* __restrict__ H) {
  const double* W = D + DWV;
  const double* Mrow = D + DMK2 + (size_t)blockIdx.x * 4096;
  __shared__ double Ms[4096];
  const int tid = threadIdx.x;
  for (int e = tid; e < 4096; e += 256) Ms[e] = Mrow[e];
  __syncthreads();
  const int c0 = blockIdx.x * 64;
  for (int e = tid; e < 4096; e += 256) {
    int i = e >> 6, r = e & 63;
    double dot = 0.0;
#pragma unroll 16
    for (int j = 0; j < 64; ++j) dot += Ms[i * 64 + j] * W[r * 64 + j];
    H[(size_t)i * NSEQ + c0 + r] = (float)dot;
  }
}

// ---------------------------------------------------------------------------
// kC: fHd[mi,k] = rfft(H[mi,:], n=4096)[k] via LDS FFT. 1 block/row.
// ---------------------------------------------------------------------------
__global__ __launch_bounds__(256) void kC_fft(const float* __restrict__ H,
                                              const float2* __restrict__ tw,
                                              float* __restrict__ fHd) {
  __shared__ float XR[FFT_LDS], XI[FFT_LDS];
  __shared__ float2 TWS[2048];
  const int tid = threadIdx.x;
  const int mi = blockIdx.x;
  const float* src = H + (size_t)mi * NSEQ;
  for (int i = tid; i < NFFT; i += 256) { XR[FIDX(i)] = 0.f; XI[FIDX(i)] = 0.f; }
  for (int i = tid; i < 2048; i += 256) TWS[i] = tw[i];
  __syncthreads();
  for (int i = tid; i < NSEQ; i += 256) {
    int r = __brev((unsigned)i) >> 20;
    XR[FIDX(r)] = src[i];
  }
  __syncthreads();
  fft4096_core(XR, XI, TWS, false);
  float2* dst = (float2*)fHd + (size_t)mi * KBINS;
  for (int k = tid; k < KBINS; k += 256)
    dst[k] = make_float2(XR[FIDX(k)], XI[FIDX(k)]);
}

// ---------------------------------------------------------------------------
// k1t: tiled GEMM out[b,o,s] = bias + sum_i Wu_w[o,i]*x[b,i,s]
//   o<256 -> dout = acc + Wu_b + Wh_b ; o>=256 -> ubuf = relu(acc + Wu_b)
// ---------------------------------------------------------------------------
__global__ __launch_bounds__(256) void k1t(
    const float* __restrict__ x, const float* __restrict__ Wuw,
    const float* __restrict__ Wub, const float* __restrict__ Whb,
    float* __restrict__ dout, float* __restrict__ ubuf) {
  __shared__ float xs[32][128];
  __shared__ float wsh[32][68];
  const int tid = threadIdx.x;
  const int b = blockIdx.z;
  const int o0 = blockIdx.y * 64;
  const int s0 = blockIdx.x * 128;
  const int sx = tid & 15, oy = tid >> 4;
  float acc[4][8];
#pragma unroll
  for (int j = 0; j < 4; ++j)
#pragma unroll
    for (int l = 0; l < 8; ++l) acc[j][l] = 0.f;

  for (int i0 = 0; i0 < 256; i0 += 32) {
#pragma unroll
    for (int e4 = tid; e4 < 1024; e4 += 256) {
      int ii = e4 >> 5, ss4 = (e4 & 31) << 2;
      float4 v = *(const float4*)&x[(size_t)(b * NIN + i0 + ii) * NSEQ + s0 + ss4];
      *(float4*)&xs[ii][ss4] = v;
    }
#pragma unroll
    for (int e4 = tid; e4 < 512; e4 += 256) {
      int oj = e4 >> 3, ii4 = (e4 & 7) << 2;
      float4 v = *(const float4*)&Wuw[(o0 + oj) * NIN + i0 + ii4];
      wsh[ii4][oj] = v.x; wsh[ii4 + 1][oj] = v.y;
      wsh[ii4 + 2][oj] = v.z; wsh[ii4 + 3][oj] = v.w;
    }
    __syncthreads();
#pragma unroll 8
    for (int kk = 0; kk < 32; ++kk) {
      float4 a = *(const float4*)&wsh[kk][oy * 4];
      float4 b0 = *(const float4*)&xs[kk][sx * 4];
      float4 b1 = *(const float4*)&xs[kk][64 + sx * 4];
      float av[4] = {a.x, a.y, a.z, a.w};
      float bv[8] = {b0.x, b0.y, b0.z, b0.w, b1.x, b1.y, b1.z, b1.w};
#pragma unroll
      for (int j = 0; j < 4; ++j)
#pragma unroll
        for (int l = 0; l < 8; ++l) acc[j][l] = fmaf(av[j], bv[l], acc[j][l]);
    }
    __syncthreads();
  }
#pragma unroll
  for (int j = 0; j < 4; ++j) {
    int o = o0 + oy * 4 + j;
    if (o < NHID) {
      float bias = Wub[o] + Whb[o];
      size_t base = ((size_t)b * NHID + o) * NSEQ + s0;
      float4 v0 = make_float4(acc[j][0] + bias, acc[j][1] + bias,
                              acc[j][2] + bias, acc[j][3] + bias);
      float4 v1 = make_float4(acc[j][4] + bias, acc[j][5] + bias,
                              acc[j][6] + bias, acc[j][7] + bias);
      *(float4*)&dout[base + sx * 4] = v0;
      *(float4*)&dout[base + 64 + sx * 4] = v1;
    } else {
      float bias = Wub[o];
      size_t base = ((size_t)b * NFEAT + (o - NHID)) * NSEQ + s0;
      float4 v0 = make_float4(fmaxf(acc[j][0] + bias, 0.f), fmaxf(acc[j][1] + bias, 0.f),
                              fmaxf(acc[j][2] + bias, 0.f), fmaxf(acc[j][3] + bias, 0.f));
      float4 v1 = make_float4(fmaxf(acc[j][4] + bias, 0.f), fmaxf(acc[j][5] + bias, 0.f),
                              fmaxf(acc[j][6] + bias, 0.f), fmaxf(acc[j][7] + bias, 0.f));
      *(float4*)&ubuf[base + sx * 4] = v0;
      *(float4*)&ubuf[base + 64 + sx * 4] = v1;
    }
  }
}

// ---------------------------------------------------------------------------
// k2f: fft_u[b,f,k] = rfft(ubuf[b,f,:], n=4096)[k] via LDS FFT. 1 block/row.
// ---------------------------------------------------------------------------
__global__ __launch_bounds__(256) void k2f(
    const float* __restrict__ ubuf, const float2* __restrict__ tw,
    float* __restrict__ fftu) {
  __shared__ float XR[FFT_LDS], XI[FFT_LDS];
  __shared__ float2 TWS[2048];
  const int tid = threadIdx.x;
  const int b = blockIdx.x >> 6, f = blockIdx.x & 63;
  const float* src = ubuf + ((size_t)b * NFEAT + f) * NSEQ;
  for (int i = tid; i < NFFT; i += 256) { XR[FIDX(i)] = 0.f; XI[FIDX(i)] = 0.f; }
  for (int i = tid; i < 2048; i += 256) TWS[i] = tw[i];
  __syncthreads();
  for (int i = tid; i < NSEQ; i += 256) {
    int r = __brev((unsigned)i) >> 20;
    XR[FIDX(r)] = src[i];
  }
  __syncthreads();
  fft4096_core(XR, XI, TWS, false);
  float2* dst = (float2*)fftu + ((size_t)b * NFEAT + f) * KBINS;
  for (int k = tid; k < KBINS; k += 256)
    dst[k] = make_float2(XR[FIDX(k)], XI[FIDX(k)]);
}

// ---------------------------------------------------------------------------
// k3o: fused G+Z for one o-chunk (32 o's), all k.
//   G[o,f,k] = sum_mi Wh_w[o, f*64+mi] * fHd[mi,k]
//   Zc[b,olocal,k] = sum_f fft_u[b,f,k] * G[o,f,k]
// Round-12 post-mortem: FETCH 37.6MB vs ~10 ideal (fftu re-fetched per XCD:
// 16 sharer blocks scattered across XCDs, 8.4MB > 4MB XCD-L2) and u-loads
// serialized after G-chain (VALUBusy 21%). Fixes:
//  (a) XCD swizzle: 1D grid 640, ktile = (wgid&7) + 8*(wgid>>7) — all 16
//      o-pair blocks of a ktile land on one XCD (wgid%8 heuristic); per-XCD
//      working set ~2MB fits L2.
//  (b) u prefetched one ff-iteration ahead (static un[8]), hiding HBM/L2
//      latency under the 64-step G FMA chain.
// ---------------------------------------------------------------------------
#define K3_SMEM 16512   // floats: WhP 8192 + fHc 8320 (64x65 float2)
__global__ __launch_bounds__(256) void k3o(
    const float* __restrict__ Whw, const float* __restrict__ fHd,
    const float* __restrict__ fftu, float* __restrict__ Zc, int ob0) {
  // XCD-aware decode (bijective over 640 wgids -> 33x16 blocks + 112 idle)
  const int wgid = blockIdx.x;
  const int cxd = wgid & 7;
  const int sdx = wgid >> 3;
  const int opair = sdx & 15;
  const int kt = cxd + 8 * (sdx >> 4);
  if (kt >= 33) return;

  __shared__ float smem[K3_SMEM];
  float2* WhP = (float2*)smem;                       // [4096]
  float2 (*fHc)[65] = (float2(*)[65])(smem + 8192);  // [64][65]
  float (*red)[64][33] = (float(*)[64][33])smem;     // overlay, post-loop only
  const int tid = threadIdx.x;
  const int ol0 = opair * 2;
  const int o0 = ob0 + ol0;
  const int k0 = kt * 64;

  for (int e = tid; e < 4096; e += 256)
    WhP[e] = make_float2(Whw[(size_t)o0 * 4096 + e],
                         Whw[(size_t)(o0 + 1) * 4096 + e]);
  for (int e = tid; e < 4096; e += 256) {
    int mi = e >> 6, kk = e & 63;
    int k = k0 + kk;
    float2 v = make_float2(0.f, 0.f);
    if (k < KBINS) v = ((const float2*)fHd)[(size_t)mi * KBINS + k];
    fHc[mi][kk] = v;
  }
  __syncthreads();

  const int tk = tid & 63, g = tid >> 6;
  const int k = k0 + tk;
  const bool kok = (k < KBINS);
  const float2* fu2 = (const float2*)fftu;
  const size_t kb = (size_t)KBINS;

  float zr[2][8], zi[2][8];
#pragma unroll
  for (int ol = 0; ol < 2; ++ol)
#pragma unroll
    for (int b = 0; b < 8; ++b) { zr[ol][b] = 0.f; zi[ol][b] = 0.f; }

  // prefetch pipeline: ub = u for current ff, un = next ff
  float2 ub[8], un[8];
#pragma unroll
  for (int b = 0; b < 8; ++b)
    ub[b] = kok ? fu2[((size_t)(b * NFEAT + g * 16)) * kb + k]
                : make_float2(0.f, 0.f);

#pragma unroll 1
  for (int ff = 0; ff < 16; ++ff) {
    const int f = g * 16 + ff;
    if (ff < 15) {
#pragma unroll
      for (int b = 0; b < 8; ++b)
        un[b] = kok ? fu2[((size_t)(b * NFEAT + f + 1)) * kb + k]
                    : make_float2(0.f, 0.f);
    }
    float g0r = 0.f, g0i = 0.f, g1r = 0.f, g1i = 0.f;
#pragma unroll 16
    for (int mi = 0; mi < 64; ++mi) {
      float2 h = fHc[mi][tk];
      float2 w = WhP[f * 64 + mi];
      g0r = fmaf(w.x, h.x, g0r); g0i = fmaf(w.x, h.y, g0i);
      g1r = fmaf(w.y, h.x, g1r); g1i = fmaf(w.y, h.y, g1i);
    }
#pragma unroll
    for (int b = 0; b < 8; ++b) {
      float2 u = ub[b];
      zr[0][b] = fmaf(u.x, g0r, fmaf(-u.y, g0i, zr[0][b]));
      zi[0][b] = fmaf(u.x, g0i, fmaf( u.y, g0r, zi[0][b]));
      zr[1][b] = fmaf(u.x, g1r, fmaf(-u.y, g1i, zr[1][b]));
      zi[1][b] = fmaf(u.x, g1i, fmaf( u.y, g1r, zi[1][b]));
    }
#pragma unroll
    for (int b = 0; b < 8; ++b) ub[b] = un[b];
  }
  __syncthreads();   // WhP/fHc dead; red overlays them
#pragma unroll
  for (int ol = 0; ol < 2; ++ol)
#pragma unroll
    for (int b = 0; b < 8; ++b) {
      red[g][tk][(ol * 8 + b) * 2 + 0] = zr[ol][b];
      red[g][tk][(ol * 8 + b) * 2 + 1] = zi[ol][b];
    }
  __syncthreads();
  if (g == 0 && kok) {
    float2* Z2 = (float2*)Zc;
#pragma unroll
    for (int ol = 0; ol < 2; ++ol)
#pragma unroll
      for (int b = 0; b < 8; ++b) {
        int i0 = (ol * 8 + b) * 2;
        float sr = red[0][tk][i0]     + red[1][tk][i0]
                 + red[2][tk][i0]     + red[3][tk][i0];
        float si = red[0][tk][i0 + 1] + red[1][tk][i0 + 1]
                 + red[2][tk][i0 + 1] + red[3][tk][i0 + 1];
        Z2[((size_t)b * OCH + ol0 + ol) * KBINS + k] = make_float2(sr, si);
      }
  }
}

// ---------------------------------------------------------------------------
// k4f: irfft via LDS FFT; dout[b,o,t] += XR[t]/4096. 1 block per (b,olocal).
// ---------------------------------------------------------------------------
__global__ __launch_bounds__(256) void k4f(
    const float* __restrict__ Zc, const float2* __restrict__ tw,
    float* __restrict__ dout, int ob0) {
  __shared__ float XR[FFT_LDS], XI[FFT_LDS];
  __shared__ float2 TWS[2048];
  const int tid = threadIdx.x;
  const int b = blockIdx.x >> 5, ol = blockIdx.x & 31;
  const int o = ob0 + ol;
  const float2* Z2 = (const float2*)Zc + ((size_t)b * OCH + ol) * KBINS;
  for (int i = tid; i < 2048; i += 256) TWS[i] = tw[i];
  for (int i = tid; i < NFFT; i += 256) {
    float2 v;
    if (i < KBINS) v = Z2[i];
    else { v = Z2[NFFT - i]; v.y = -v.y; }
    int r = __brev((unsigned)i) >> 20;
    XR[FIDX(r)] = v.x; XI[FIDX(r)] = v.y;
  }
  __syncthreads();
  fft4096_core(XR, XI, TWS, true);
  const float inv = 1.0f / (float)NFFT;
  float* drow = dout + ((size_t)b * NHID + o) * NSEQ;
  for (int t = tid; t < NSEQ; t += 256)
    drow[t] += XR[FIDX(t)] * inv;
}

// ---------------------------------------------------------------------------
extern "C" void kernel_launch(void* const* d_in, const int* in_sizes, int n_in,
                              void* d_out, int out_size, void* d_ws, size_t ws_size,
                              hipStream_t stream) {
  const float* x   = (const float*)d_in[0];
  const float* Wuw = (const float*)d_in[1];
  const float* Wub = (const float*)d_in[2];
  const float* Whw = (const float*)d_in[3];
  const float* Whb = (const float*)d_in[4];
  // d_in[5] (fft_H) intentionally UNUSED: recomputed on-device in fp64.
  float* out = (float*)d_out;
  float* ws  = (float*)d_ws;

  float* fftu = ws + FFTU_OFF;
  float* uz   = ws + UZ_OFF;       // f64 scratch -> ubuf -> Z o-chunks
  float* fHd  = ws + FHD_OFF;
  float2* tw  = (float2*)(ws + TW_OFF);
  float* Hbuf = ws + HBUF_OFF;
  double* D   = (double*)uz;

  k0_tw<<<8, 256, 0, stream>>>(tw);

  // --- kA chain: expm + power tables ---
  kblk<<<17, 256, 0, stream>>>(D + DMM);
  kinitTE<<<17, 256, 0, stream>>>(D + DTT0, D + DEE0);
  {
    double* t0 = D + DTT0;
    double* t1 = D + DTT1;
    for (int k = 1; k <= 16; ++k) {
      kmm65<<<17, 256, 0, stream>>>(t0, D + DMM, t1, D + DEE0, (double)k);
      double* tmp = t0; t0 = t1; t1 = tmp;
    }
  }
  kmm65<<<17, 256, 0, stream>>>(D + DEE0, D + DEE0, D + DEE1, (double*)nullptr, 1.0);
  kmm65<<<17, 256, 0, stream>>>(D + DEE1, D + DEE1, D + DEE0, (double*)nullptr, 1.0);
  kext<<<17, 256, 0, stream>>>(D + DEE0, D);
  for (int m = 1; m <= 5; ++m)
    kmm64<<<16, 256, 0, stream>>>(D + DPW + (m - 1) * 4096,
                                  D + DPW + (m - 1) * 4096,
                                  D + DPW + m * 4096);
  kmm64<<<16, 256, 0, stream>>>(D + DPW + 5 * 4096, D + DPW + 5 * 4096,
                                D + DMK2 + 4096);
  for (int m = 0; m <= 5; ++m)
    kwlev<<<1, 256, 0, stream>>>(D + DPW + m * 4096, D + DWV, 1 << m);
  for (int m = 1; m <= 4; ++m) {
    int b0 = 1 << m;
    kmm64<<<16, 256, 0, stream>>>(D + DMK2 + (size_t)(b0 / 2) * 4096,
                                  D + DMK2 + (size_t)(b0 / 2) * 4096,
                                  D + DMK2 + (size_t)b0 * 4096);
    int cnt = b0 - 1;
    kmk<<<dim3(16, cnt), 256, 0, stream>>>(D + DMK2 + (size_t)b0 * 4096,
                                           D + DMK2 + 4096,
                                           D + DMK2 + (size_t)(b0 + 1) * 4096);
  }

  kB_cols<<<32, 256, 0, stream>>>(D, Hbuf);
  kC_fft<<<NMEM, 256, 0, stream>>>(Hbuf, tw, fHd);
  k1t<<<dim3(NSEQ / 128, NOUTCH / 64, NB), 256, 0, stream>>>(x, Wuw, Wub, Whb, out, uz);
  k2f<<<NB * NFEAT, 256, 0, stream>>>(uz, tw, fftu);
  for (int oc = 0; oc < NOCH; ++oc) {
    int ob0 = oc * OCH;
    k3o<<<640, 256, 0, stream>>>(Whw, fHd, fftu, uz, ob0);
    k4f<<<NB * OCH, 256, 0, stream>>>(uz, tw, out, ob0);
  }
}